// Round 2
// baseline (7807.693 us; speedup 1.0000x reference)
//
#include <hip/hip_runtime.h>
#include <hip/hip_bf16.h>
#include <math.h>

// Problem constants
constexpr int Bn = 4, Tn = 2048, Dn = 1024, Hn = 16, DKn = 48, DVn = 96, In = 3072;
constexpr int BT = Bn * Tn;               // 8192
constexpr int HDK = Hn * DKn;             // 768
constexpr int HDV = Hn * DVn;             // 1536
constexpr int QKVC = 2 * HDK + HDV;       // 3072

// Workspace layout (float offsets) — total 58,982,400 floats = 235,929,600 B (< 256 MiB)
constexpr size_t O_H    = 0;               // 8192*1024  (h; later h2)
constexpr size_t O_QKV  = 8388608;         // 8192*3072  (qkv; later attn; later mlp act)
constexpr size_t O_GATE = 33554432;        // 8192*1536  (gate proj)
constexpr size_t O_O    = 46137344;        // 8192*1536  (scan out; later x1)
constexpr size_t O_BA   = 58720256;        // 8192*32    (beta|g; dead before x1 needs nothing here)
// end = 58982400 floats

__device__ __forceinline__ float sigmoidf(float x) { return 1.f / (1.f + __expf(-x)); }
__device__ __forceinline__ float siluf(float x) { return x * sigmoidf(x); }

// ---------------- RMSNorm over 1024 cols, one block (256 thr) per row ----------------
__global__ void rmsnorm_k(const float* __restrict__ x, const float* __restrict__ w,
                          float* __restrict__ y) {
  int row = blockIdx.x;
  const float4* xr = (const float4*)(x + (size_t)row * Dn);
  float4* yr = (float4*)(y + (size_t)row * Dn);
  int tid = threadIdx.x;
  float4 v = xr[tid];
  float ss = v.x * v.x + v.y * v.y + v.z * v.z + v.w * v.w;
  for (int m = 32; m >= 1; m >>= 1) ss += __shfl_xor(ss, m, 64);
  __shared__ float wsum[4];
  if ((tid & 63) == 0) wsum[tid >> 6] = ss;
  __syncthreads();
  ss = wsum[0] + wsum[1] + wsum[2] + wsum[3];
  float rs = rsqrtf(ss * (1.f / Dn) + 1e-5f);
  float4 wv = ((const float4*)w)[tid];
  float4 o;
  o.x = v.x * rs * wv.x; o.y = v.y * rs * wv.y;
  o.z = v.z * rs * wv.z; o.w = v.w * rs * wv.w;
  yr[tid] = o;
}

// ---------------- Generic tiled fp32 GEMM: C[M,N] = A[M,K]@B[K,N] ----------------
// 64x64 tile, 256 threads, 4x4 micro-tile. M%64==0, K%16==0 assumed; N guarded.
// mode: 0 = C=acc(+res), 1 = C=silu(acc), 2 = C=acc*C_old (in-place multiply)
__global__ __launch_bounds__(256) void gemm64(
    const float* __restrict__ A, int lda,
    const float* __restrict__ Bm, int ldb,
    float* __restrict__ C, int ldc,
    const float* __restrict__ res, int ldr,
    int M, int N, int Kd, int mode) {
  __shared__ float As[16][68];
  __shared__ float Bs[16][68];
  int bm = blockIdx.y * 64, bn = blockIdx.x * 64;
  int tid = threadIdx.x;
  int tx = tid & 15, ty = tid >> 4;
  float acc[4][4] = {};
  for (int k0 = 0; k0 < Kd; k0 += 16) {
#pragma unroll
    for (int p = 0; p < 4; p++) {
      int l = tid + 256 * p;
      int r = l >> 4, kk = l & 15;
      As[kk][r] = A[(size_t)(bm + r) * lda + k0 + kk];
    }
#pragma unroll
    for (int p = 0; p < 4; p++) {
      int l = tid + 256 * p;
      int kk = l >> 6, c = l & 63;
      int col = bn + c;
      Bs[kk][c] = (col < N) ? Bm[(size_t)(k0 + kk) * ldb + col] : 0.f;
    }
    __syncthreads();
#pragma unroll
    for (int kk = 0; kk < 16; kk++) {
      float4 a4 = *(const float4*)&As[kk][ty * 4];
      float4 b4 = *(const float4*)&Bs[kk][tx * 4];
      float a[4] = {a4.x, a4.y, a4.z, a4.w};
      float b[4] = {b4.x, b4.y, b4.z, b4.w};
#pragma unroll
      for (int i = 0; i < 4; i++)
#pragma unroll
        for (int j = 0; j < 4; j++) acc[i][j] += a[i] * b[j];
    }
    __syncthreads();
  }
#pragma unroll
  for (int i = 0; i < 4; i++) {
    int r = bm + ty * 4 + i;
#pragma unroll
    for (int j = 0; j < 4; j++) {
      int c = bn + tx * 4 + j;
      if (c < N) {
        float v = acc[i][j];
        if (mode == 1) v = siluf(v);
        else if (mode == 2) v *= C[(size_t)r * ldc + c];
        else if (res) v += res[(size_t)r * ldr + c];
        C[(size_t)r * ldc + c] = v;
      }
    }
  }
}

// ---------------- Causal depthwise conv (K=4) + silu, in place on [B,T,3072] ----------------
__global__ void convsilu_k(float* __restrict__ qkv, const float* __restrict__ wq,
                           const float* __restrict__ wk, const float* __restrict__ wv) {
  int gid = blockIdx.x * blockDim.x + threadIdx.x;  // B*3072
  int c = gid % QKVC, b = gid / QKVC;
  const float* w = (c < HDK) ? (wq + c * 4)
                   : (c < 2 * HDK) ? (wk + (c - HDK) * 4)
                                   : (wv + (c - 2 * HDK) * 4);
  float w0 = w[0], w1 = w[1], w2 = w[2], w3 = w[3];
  float x0 = 0.f, x1 = 0.f, x2 = 0.f;  // x[t-3], x[t-2], x[t-1]
  float* p = qkv + (size_t)b * Tn * QKVC + c;
  for (int t = 0; t < Tn; t++) {
    float xt = p[(size_t)t * QKVC];
    float y = x0 * w0 + x1 * w1 + x2 * w2 + xt * w3;
    p[(size_t)t * QKVC] = siluf(y);
    x0 = x1; x1 = x2; x2 = xt;
  }
}

// ---------------- l2norm over 48-element head rows of q,k (in place) ----------------
__global__ void l2norm_k(float* __restrict__ qkv) {
  int wid = (blockIdx.x * blockDim.x + threadIdx.x) >> 6;
  int lane = threadIdx.x & 63;
  int t = wid >> 5, hr = wid & 31;  // 32 head-rows per token (16 q + 16 k)
  float* p = qkv + (size_t)t * QKVC + hr * DKn;
  float v = (lane < DKn) ? p[lane] : 0.f;
  float ss = v * v;
  for (int m = 32; m >= 1; m >>= 1) ss += __shfl_xor(ss, m, 64);
  float rs = rsqrtf(ss + 1e-6f);
  if (lane < DKn) p[lane] = v * rs;
}

// ---------------- beta = sigmoid(b), g = -exp(A_log)*softplus(a + dt_bias), in place ----------------
__global__ void betag_k(float* __restrict__ ba, const float* __restrict__ A_log,
                        const float* __restrict__ dt_bias) {
  int i = blockIdx.x * blockDim.x + threadIdx.x;  // BT*16
  int h = i & 15, r = i >> 4;
  float bv = ba[(size_t)r * 32 + h];
  float av = ba[(size_t)r * 32 + 16 + h];
  ba[(size_t)r * 32 + h] = sigmoidf(bv);
  float xx = av + dt_bias[h];
  float sp = (xx > 20.f) ? xx : log1pf(__expf(xx));
  ba[(size_t)r * 32 + 16 + h] = -__expf(A_log[h]) * sp;
}

// ---------------- gated delta rule scan: one block per (b,h), 96 threads (one per dv) ----------------
__global__ void scan_k(const float* __restrict__ qkv, const float* __restrict__ ba,
                       float* __restrict__ o) {
  int b = blockIdx.x >> 4, h = blockIdx.x & 15;
  int j = threadIdx.x;  // 0..95
  const float scale = 0.14433756729740643f;  // 48^-0.5
  float S[DKn];
#pragma unroll
  for (int d = 0; d < DKn; d++) S[d] = 0.f;
  const float* qb = qkv + (size_t)b * Tn * QKVC + h * DKn;
  const float* kb = qb + HDK;
  const float* vb = qkv + (size_t)b * Tn * QKVC + 2 * HDK + h * DVn + j;
  const float* bab = ba + (size_t)b * Tn * 32;
  float* ob = o + (size_t)b * Tn * HDV + h * DVn + j;
  for (int t = 0; t < Tn; t++) {
    const float* kr = kb + (size_t)t * QKVC;
    const float* qr = qb + (size_t)t * QKVC;
    float g = bab[t * 32 + 16 + h];
    float be = bab[t * 32 + h];
    float eg = __expf(g);
    float vj = vb[(size_t)t * QKVC];
    float kv = 0.f;
#pragma unroll
    for (int d = 0; d < DKn; d++) {
      S[d] *= eg;
      kv += kr[d] * S[d];
    }
    float vn = (vj - kv) * be;
    float ot = 0.f;
#pragma unroll
    for (int d = 0; d < DKn; d++) {
      S[d] += kr[d] * vn;
      ot += qr[d] * S[d];
    }
    ob[(size_t)t * HDV] = ot * scale;
  }
}

// ---------------- fused gated RMSNorm: attn = rmsnorm(o)*o_norm_w * silu(gate), wave per row ----------------
__global__ void gatednorm_k(const float* __restrict__ o, const float* __restrict__ gate,
                            const float* __restrict__ onw, float* __restrict__ attn) {
  int wid = (blockIdx.x * blockDim.x + threadIdx.x) >> 6;  // row in [0, BT*H)
  int lane = threadIdx.x & 63;
  const float* orow = o + (size_t)wid * DVn;
  const float* grow = gate + (size_t)wid * DVn;
  float* arow = attn + (size_t)wid * DVn;
  float v0 = orow[lane];
  float v1 = (lane < 32) ? orow[64 + lane] : 0.f;
  float ss = v0 * v0 + v1 * v1;
  for (int m = 32; m >= 1; m >>= 1) ss += __shfl_xor(ss, m, 64);
  float rs = rsqrtf(ss * (1.f / DVn) + 1e-5f);
  float g0 = grow[lane];
  arow[lane] = v0 * rs * onw[lane] * siluf(g0);
  if (lane < 32) {
    float g1 = grow[64 + lane];
    arow[64 + lane] = v1 * rs * onw[64 + lane] * siluf(g1);
  }
}

extern "C" void kernel_launch(void* const* d_in, const int* in_sizes, int n_in,
                              void* d_out, int out_size, void* d_ws, size_t ws_size,
                              hipStream_t stream) {
  const float* x       = (const float*)d_in[0];
  const float* norm1_w = (const float*)d_in[1];
  const float* q_w     = (const float*)d_in[2];
  const float* k_w     = (const float*)d_in[3];
  const float* v_w     = (const float*)d_in[4];
  const float* cq_w    = (const float*)d_in[5];
  const float* ck_w    = (const float*)d_in[6];
  const float* cv_w    = (const float*)d_in[7];
  const float* b_w     = (const float*)d_in[8];
  const float* a_w     = (const float*)d_in[9];
  const float* A_log   = (const float*)d_in[10];
  const float* dt_bias = (const float*)d_in[11];
  const float* g_w     = (const float*)d_in[12];
  const float* o_norm_w= (const float*)d_in[13];
  const float* o_w     = (const float*)d_in[14];
  const float* norm2_w = (const float*)d_in[15];
  const float* gate_w  = (const float*)d_in[16];
  const float* up_w    = (const float*)d_in[17];
  const float* down_w  = (const float*)d_in[18];
  float* ws = (float*)d_ws;
  float* out = (float*)d_out;

  float* h    = ws + O_H;
  float* qkv  = ws + O_QKV;
  float* ba   = ws + O_BA;
  float* gate = ws + O_GATE;
  float* osc  = ws + O_O;
  float* x1   = ws + O_O;     // reuse scan-out region (osc dead after gatednorm)
  float* attn = ws + O_QKV;   // reuse qkv region after scan
  float* h2   = ws + O_H;     // reuse h region
  float* mlpg = ws + O_QKV;   // reuse attn region after o_w gemm

  // 1. h = rmsnorm(x, norm1_w)
  rmsnorm_k<<<BT, 256, 0, stream>>>(x, norm1_w, h);

  // 2. q,k,v projections into qkv [BT, 3072]
  gemm64<<<dim3(HDK / 64, BT / 64), 256, 0, stream>>>(h, Dn, q_w, HDK, qkv, QKVC, nullptr, 0, BT, HDK, Dn, 0);
  gemm64<<<dim3(HDK / 64, BT / 64), 256, 0, stream>>>(h, Dn, k_w, HDK, qkv + HDK, QKVC, nullptr, 0, BT, HDK, Dn, 0);
  gemm64<<<dim3(HDV / 64, BT / 64), 256, 0, stream>>>(h, Dn, v_w, HDV, qkv + 2 * HDK, QKVC, nullptr, 0, BT, HDV, Dn, 0);

  // 3. b,a projections into ba [BT, 32]
  gemm64<<<dim3(1, BT / 64), 256, 0, stream>>>(h, Dn, b_w, Hn, ba, 32, nullptr, 0, BT, Hn, Dn, 0);
  gemm64<<<dim3(1, BT / 64), 256, 0, stream>>>(h, Dn, a_w, Hn, ba + 16, 32, nullptr, 0, BT, Hn, Dn, 0);

  // 4. gate projection [BT, 1536]
  gemm64<<<dim3(HDV / 64, BT / 64), 256, 0, stream>>>(h, Dn, g_w, HDV, gate, HDV, nullptr, 0, BT, HDV, Dn, 0);

  // 5. causal conv + silu in place
  convsilu_k<<<(Bn * QKVC) / 256, 256, 0, stream>>>(qkv, cq_w, ck_w, cv_w);

  // 6. l2norm on q,k head rows
  l2norm_k<<<(BT * 32) / 4, 256, 0, stream>>>(qkv);

  // 7. beta/g transform
  betag_k<<<(BT * Hn) / 256, 256, 0, stream>>>(ba, A_log, dt_bias);

  // 8. gated delta rule scan -> osc [BT, 1536]
  scan_k<<<Bn * Hn, 96, 0, stream>>>(qkv, ba, osc);

  // 9. gated RMSNorm -> attn [BT, 1536] (into qkv region)
  gatednorm_k<<<(BT * Hn) / 4, 256, 0, stream>>>(osc, gate, o_norm_w, attn);

  // 10. x1 = x + attn @ o_w   (x1 overwrites osc region — osc is dead)
  gemm64<<<dim3(Dn / 64, BT / 64), 256, 0, stream>>>(attn, HDV, o_w, Dn, x1, Dn, x, Dn, BT, Dn, HDV, 0);

  // 11. h2 = rmsnorm(x1, norm2_w)
  rmsnorm_k<<<BT, 256, 0, stream>>>(x1, norm2_w, h2);

  // 12. mlpg = silu(h2 @ gate_w), then mlpg *= h2 @ up_w  (fused epilogues, no up buffer)
  gemm64<<<dim3(In / 64, BT / 64), 256, 0, stream>>>(h2, Dn, gate_w, In, mlpg, In, nullptr, 0, BT, In, Dn, 1);
  gemm64<<<dim3(In / 64, BT / 64), 256, 0, stream>>>(h2, Dn, up_w, In, mlpg, In, nullptr, 0, BT, In, Dn, 2);

  // 13. out = x1 + act @ down_w
  gemm64<<<dim3(Dn / 64, BT / 64), 256, 0, stream>>>(mlpg, In, down_w, Dn, out, Dn, x1, Dn, BT, Dn, In, 0);
}

// Round 3
// 3292.813 us; speedup vs baseline: 2.3711x; 2.3711x over previous
//
#include <hip/hip_runtime.h>
#include <hip/hip_bf16.h>
#include <math.h>

// Problem constants
constexpr int Bn = 4, Tn = 2048, Dn = 1024, Hn = 16, DKn = 48, DVn = 96, In = 3072;
constexpr int BT = Bn * Tn;               // 8192
constexpr int HDK = Hn * DKn;             // 768
constexpr int HDV = Hn * DVn;             // 1536
constexpr int QKVC = 2 * HDK + HDV;       // 3072

using bf16 = __hip_bfloat16;
typedef __attribute__((ext_vector_type(8))) short bf16x8;
typedef __attribute__((ext_vector_type(4))) float f32x4;

// ---- Workspace layout (byte offsets) — total 250,675,200 B < 256 MiB ----
constexpr size_t WO_HBF  = 0;                    // h_bf / h2_bf   8192*1024*2  = 16 MB
constexpr size_t WO_QKV  = 16777216;             // qkv fp32 96MB; later attn_bf / actbf
constexpr size_t WO_GATE = 117440512;            // gate fp32 48MB
constexpr size_t WO_OSC  = 167772160;            // osc fp32 48MB; later x1 fp32 32MB
constexpr size_t WO_BA   = 218103808;            // ba fp32 1MB
constexpr size_t WO_WB   = 219152384;            // bf16 weights ~31.5MB
// bf16-element offsets inside WB:
constexpr size_t WB_QKVT = 0;                    // [3072][1024] (q rows 0-767, k 768-1535, v 1536-3071)
constexpr size_t WB_GT   = 3145728;              // [1536][1024]
constexpr size_t WB_OT   = 4718592;              // [1024][1536]
constexpr size_t WB_GATET= 6291456;              // [3072][1024]
constexpr size_t WB_UPT  = 9437184;              // [3072][1024]
constexpr size_t WB_DOWNT= 12582912;             // [1024][3072]
constexpr size_t WB_ABT  = 15728640;             // [32][1024] (b rows 0-15, a rows 16-31)

__device__ __forceinline__ float sigmoidf_(float x) { return 1.f / (1.f + __expf(-x)); }
__device__ __forceinline__ float siluf(float x) { return x * sigmoidf_(x); }

__device__ __forceinline__ void glds16(const void* g, void* l) {
  __builtin_amdgcn_global_load_lds((const __attribute__((address_space(1))) void*)g,
                                   (__attribute__((address_space(3))) void*)l, 16, 0, 0);
}

// ---------------- transpose-cast: in fp32 [R][C] -> out bf16 [C][R] ----------------
__global__ void tcast_k(const float* __restrict__ in, bf16* __restrict__ out, int R, int C) {
  __shared__ float t[32][33];
  int tx = threadIdx.x, ty = threadIdx.y;
  int c0 = blockIdx.x * 32, r0 = blockIdx.y * 32;
#pragma unroll
  for (int j = 0; j < 4; j++) {
    int r = ty + j * 8;
    float v = (c0 + tx < C) ? in[(size_t)(r0 + r) * C + c0 + tx] : 0.f;
    t[r][tx] = v;
  }
  __syncthreads();
#pragma unroll
  for (int j = 0; j < 4; j++) {
    int cc = ty + j * 8;
    if (c0 + cc < C) out[(size_t)(c0 + cc) * R + r0 + tx] = __float2bfloat16(t[tx][cc]);
  }
}

// ---------------- RMSNorm -> bf16 out ----------------
__global__ void rmsnorm_bf_k(const float* __restrict__ x, const float* __restrict__ w,
                             bf16* __restrict__ y) {
  int row = blockIdx.x;
  const float4* xr = (const float4*)(x + (size_t)row * Dn);
  int tid = threadIdx.x;
  float4 v = xr[tid];
  float ss = v.x * v.x + v.y * v.y + v.z * v.z + v.w * v.w;
  for (int m = 32; m >= 1; m >>= 1) ss += __shfl_xor(ss, m, 64);
  __shared__ float wsum[4];
  if ((tid & 63) == 0) wsum[tid >> 6] = ss;
  __syncthreads();
  ss = wsum[0] + wsum[1] + wsum[2] + wsum[3];
  float rs = rsqrtf(ss * (1.f / Dn) + 1e-5f);
  float4 wv = ((const float4*)w)[tid];
  bf16* yr = y + (size_t)row * Dn + tid * 4;
  yr[0] = __float2bfloat16(v.x * rs * wv.x);
  yr[1] = __float2bfloat16(v.y * rs * wv.y);
  yr[2] = __float2bfloat16(v.z * rs * wv.z);
  yr[3] = __float2bfloat16(v.w * rs * wv.w);
}

// ---------------- MFMA bf16 GEMM: C[8192,N] = A[8192,K] @ Bt[N,K]^T ----------------
// 128x128 tile, BK=32, 4 waves, global_load_lds staging with XOR-quad swizzle.
// mode 0: fp32 out (+res). mode 1: bf16 out = silu(acc). mode 2: bf16 out = C_old*acc.
__global__ __launch_bounds__(256) void gemm_mfma(
    const bf16* __restrict__ A, const bf16* __restrict__ Bt,
    void* __restrict__ Cv, const float* __restrict__ res,
    int N, int K, int ldc, int mode) {
  __shared__ bf16 As[128 * 32];
  __shared__ bf16 Bs[128 * 32];
  int tid = threadIdx.x, lane = tid & 63, w = tid >> 6;
  int bm = blockIdx.y * 128, bn = blockIdx.x * 128;
  int wr = w >> 1, wc = w & 1;
  int srow = lane >> 2;                       // 0..15 (staging row within chunk)
  int gq = (lane & 3) ^ ((lane >> 3) & 3);    // staging source quad (swizzle involution)
  int qa = (lane >> 4) ^ ((lane >> 1) & 3);   // frag-read quad
  int arow_base = wr * 64 + (lane & 15);
  int brow_base = wc * 64 + (lane & 15);
  f32x4 acc[4][4];
#pragma unroll
  for (int m = 0; m < 4; m++)
#pragma unroll
    for (int n = 0; n < 4; n++) acc[m][n] = (f32x4){0.f, 0.f, 0.f, 0.f};

  for (int k0 = 0; k0 < K; k0 += 32) {
#pragma unroll
    for (int cc = 0; cc < 2; cc++) {
      int c = 2 * w + cc;
      int arow = bm + c * 16 + srow;
      glds16(A + (size_t)arow * K + k0 + gq * 8, &As[c * 512]);
      int brow = bn + c * 16 + srow; if (brow >= N) brow = 0;
      glds16(Bt + (size_t)brow * K + k0 + gq * 8, &Bs[c * 512]);
    }
    __syncthreads();
    bf16x8 af[4], bfr[4];
#pragma unroll
    for (int m = 0; m < 4; m++) {
      int r = arow_base + m * 16;
      af[m] = *(const bf16x8*)&As[r * 32 + qa * 8];
    }
#pragma unroll
    for (int n = 0; n < 4; n++) {
      int r = brow_base + n * 16;
      bfr[n] = *(const bf16x8*)&Bs[r * 32 + qa * 8];
    }
#pragma unroll
    for (int m = 0; m < 4; m++)
#pragma unroll
      for (int n = 0; n < 4; n++)
        acc[m][n] = __builtin_amdgcn_mfma_f32_16x16x32_bf16(af[m], bfr[n], acc[m][n], 0, 0, 0);
    __syncthreads();
  }
  // epilogue: D lane map col=lane&15, row=(lane>>4)*4+i
#pragma unroll
  for (int m = 0; m < 4; m++) {
#pragma unroll
    for (int n = 0; n < 4; n++) {
      int col = bn + wc * 64 + n * 16 + (lane & 15);
      if (col >= N) continue;
#pragma unroll
      for (int i = 0; i < 4; i++) {
        int row = bm + wr * 64 + m * 16 + (lane >> 4) * 4 + i;
        float v = acc[m][n][i];
        size_t idx = (size_t)row * ldc + col;
        if (mode == 0) {
          if (res) v += res[idx];
          ((float*)Cv)[idx] = v;
        } else if (mode == 1) {
          ((bf16*)Cv)[idx] = __float2bfloat16(siluf(v));
        } else {
          bf16* Cp = (bf16*)Cv;
          float old = __bfloat162float(Cp[idx]);
          Cp[idx] = __float2bfloat16(old * v);
        }
      }
    }
  }
}

// ---------------- Causal depthwise conv (K=4) + silu, in place on [B,T,3072] ----------------
__global__ void convsilu_k(float* __restrict__ qkv, const float* __restrict__ wq,
                           const float* __restrict__ wk, const float* __restrict__ wv) {
  int gid = blockIdx.x * blockDim.x + threadIdx.x;  // B*3072
  int c = gid % QKVC, b = gid / QKVC;
  const float* w = (c < HDK) ? (wq + c * 4)
                   : (c < 2 * HDK) ? (wk + (c - HDK) * 4)
                                   : (wv + (c - 2 * HDK) * 4);
  float w0 = w[0], w1 = w[1], w2 = w[2], w3 = w[3];
  float x0 = 0.f, x1 = 0.f, x2 = 0.f;
  float* p = qkv + (size_t)b * Tn * QKVC + c;
  for (int t = 0; t < Tn; t++) {
    float xt = p[(size_t)t * QKVC];
    float y = x0 * w0 + x1 * w1 + x2 * w2 + xt * w3;
    p[(size_t)t * QKVC] = siluf(y);
    x0 = x1; x1 = x2; x2 = xt;
  }
}

// ---------------- l2norm over 48-element head rows of q,k (in place) ----------------
__global__ void l2norm_k(float* __restrict__ qkv) {
  int wid = (blockIdx.x * blockDim.x + threadIdx.x) >> 6;
  int lane = threadIdx.x & 63;
  int t = wid >> 5, hr = wid & 31;
  float* p = qkv + (size_t)t * QKVC + hr * DKn;
  float v = (lane < DKn) ? p[lane] : 0.f;
  float ss = v * v;
  for (int m = 32; m >= 1; m >>= 1) ss += __shfl_xor(ss, m, 64);
  float rs = rsqrtf(ss + 1e-6f);
  if (lane < DKn) p[lane] = v * rs;
}

// ---------------- beta = sigmoid(b), g = -exp(A_log)*softplus(a+dt_bias), in place ----------------
__global__ void betag_k(float* __restrict__ ba, const float* __restrict__ A_log,
                        const float* __restrict__ dt_bias) {
  int i = blockIdx.x * blockDim.x + threadIdx.x;  // BT*16
  int h = i & 15, r = i >> 4;
  float bv = ba[(size_t)r * 32 + h];
  float av = ba[(size_t)r * 32 + 16 + h];
  ba[(size_t)r * 32 + h] = sigmoidf_(bv);
  float xx = av + dt_bias[h];
  float sp = (xx > 20.f) ? xx : log1pf(__expf(xx));
  ba[(size_t)r * 32 + 16 + h] = -__expf(A_log[h]) * sp;
}

// ---------------- gated delta rule scan v2 ----------------
// 128 blocks (b,h,half: 48 dv cols each), 64 threads (1 wave), LDS double-buffered
// tiles of 32 timesteps staged via global_load_lds; g/beta preloaded whole.
__global__ __launch_bounds__(64) void scan2_k(const float* __restrict__ qkv,
                                              const float* __restrict__ ba,
                                              float* __restrict__ o) {
  __shared__ float ks[2][32][48];
  __shared__ float qs[2][32][48];
  __shared__ float vs[2][32][48];
  __shared__ float gbeta[2048];
  __shared__ float gg[2048];
  int blk = blockIdx.x;
  int half = blk & 1, h = (blk >> 1) & 15, b = blk >> 5;
  int tid = threadIdx.x;
  // preload g/beta for whole sequence
  const float* bab = ba + (size_t)b * Tn * 32;
  for (int i = tid; i < Tn; i += 64) {
    gbeta[i] = bab[(size_t)i * 32 + h];
    gg[i]    = bab[(size_t)i * 32 + 16 + h];
  }
  const float* base = qkv + (size_t)b * Tn * QKVC;
  int qcol = h * DKn, kcol = HDK + h * DKn, vcol = 2 * HDK + h * DVn + half * 48;
  // staging geometry: chunk c (0..5): lane byte L = c*1024 + lane*16
  // row = (c*64+lane)/12, colf = ((c*64+lane)%12)*4   (row stride 48 floats = 192B)
  float S[48];
#pragma unroll
  for (int d = 0; d < 48; d++) S[d] = 0.f;
  int cur = 0;
  const float scale = 0.14433756729740643f;  // 48^-0.5
  float* ob = o + (size_t)b * Tn * HDV + h * DVn + half * 48 + tid;
  const int NT = Tn / 32;

  // prologue stage tile 0 -> buf 0
  {
#pragma unroll
    for (int c = 0; c < 6; c++) {
      int e = c * 64 + tid;
      int row = e / 12, colf = (e % 12) * 4;
      const float* gr = base + (size_t)row * QKVC;
      glds16(gr + kcol + colf, &ks[0][0][0] + c * 256);
      glds16(gr + qcol + colf, &qs[0][0][0] + c * 256);
      glds16(gr + vcol + colf, &vs[0][0][0] + c * 256);
    }
  }
  for (int tt = 0; tt < NT; tt++) {
    __syncthreads();  // drains glds of buf[cur] (+ lgkm for gbeta/gg on tt=0)
    if (tt + 1 < NT) {
      int t0 = (tt + 1) * 32;
      int bb = cur ^ 1;
#pragma unroll
      for (int c = 0; c < 6; c++) {
        int e = c * 64 + tid;
        int row = t0 + e / 12, colf = (e % 12) * 4;
        const float* gr = base + (size_t)row * QKVC;
        glds16(gr + kcol + colf, &ks[bb][0][0] + c * 256);
        glds16(gr + qcol + colf, &qs[bb][0][0] + c * 256);
        glds16(gr + vcol + colf, &vs[bb][0][0] + c * 256);
      }
    }
    if (tid < 48) {
      for (int i = 0; i < 32; i++) {
        int t = tt * 32 + i;
        float eg = __expf(gg[t]);
        float be = gbeta[t];
        float vj = vs[cur][i][tid];
        const float4* kr = (const float4*)&ks[cur][i][0];
        const float4* qr = (const float4*)&qs[cur][i][0];
        float kv0 = 0, kv1 = 0, kv2 = 0, kv3 = 0;
#pragma unroll
        for (int d4 = 0; d4 < 12; d4++) {
          float4 kk = kr[d4];
          kv0 += kk.x * S[d4 * 4 + 0]; kv1 += kk.y * S[d4 * 4 + 1];
          kv2 += kk.z * S[d4 * 4 + 2]; kv3 += kk.w * S[d4 * 4 + 3];
        }
        float kv = ((kv0 + kv1) + (kv2 + kv3)) * eg;
        float vn = (vj - kv) * be;
        float o0 = 0, o1 = 0, o2 = 0, o3 = 0;
#pragma unroll
        for (int d4 = 0; d4 < 12; d4++) {
          float4 kk = kr[d4];
          float4 qq = qr[d4];
          float s0 = S[d4 * 4 + 0] * eg + kk.x * vn; S[d4 * 4 + 0] = s0; o0 += qq.x * s0;
          float s1 = S[d4 * 4 + 1] * eg + kk.y * vn; S[d4 * 4 + 1] = s1; o1 += qq.y * s1;
          float s2 = S[d4 * 4 + 2] * eg + kk.z * vn; S[d4 * 4 + 2] = s2; o2 += qq.z * s2;
          float s3 = S[d4 * 4 + 3] * eg + kk.w * vn; S[d4 * 4 + 3] = s3; o3 += qq.w * s3;
        }
        ob[(size_t)t * HDV] = ((o0 + o1) + (o2 + o3)) * scale;
      }
    }
    cur ^= 1;
  }
}

// ---------------- fused gated RMSNorm -> bf16 ----------------
__global__ void gatednorm_bf_k(const float* __restrict__ o, const float* __restrict__ gate,
                               const float* __restrict__ onw, bf16* __restrict__ attn) {
  int wid = (blockIdx.x * blockDim.x + threadIdx.x) >> 6;
  int lane = threadIdx.x & 63;
  const float* orow = o + (size_t)wid * DVn;
  const float* grow = gate + (size_t)wid * DVn;
  bf16* arow = attn + (size_t)wid * DVn;
  float v0 = orow[lane];
  float v1 = (lane < 32) ? orow[64 + lane] : 0.f;
  float ss = v0 * v0 + v1 * v1;
  for (int m = 32; m >= 1; m >>= 1) ss += __shfl_xor(ss, m, 64);
  float rs = rsqrtf(ss * (1.f / DVn) + 1e-5f);
  float g0 = grow[lane];
  arow[lane] = __float2bfloat16(v0 * rs * onw[lane] * siluf(g0));
  if (lane < 32) {
    float g1 = grow[64 + lane];
    arow[64 + lane] = __float2bfloat16(v1 * rs * onw[64 + lane] * siluf(g1));
  }
}

extern "C" void kernel_launch(void* const* d_in, const int* in_sizes, int n_in,
                              void* d_out, int out_size, void* d_ws, size_t ws_size,
                              hipStream_t stream) {
  const float* x       = (const float*)d_in[0];
  const float* norm1_w = (const float*)d_in[1];
  const float* q_w     = (const float*)d_in[2];
  const float* k_w     = (const float*)d_in[3];
  const float* v_w     = (const float*)d_in[4];
  const float* cq_w    = (const float*)d_in[5];
  const float* ck_w    = (const float*)d_in[6];
  const float* cv_w    = (const float*)d_in[7];
  const float* b_w     = (const float*)d_in[8];
  const float* a_w     = (const float*)d_in[9];
  const float* A_log   = (const float*)d_in[10];
  const float* dt_bias = (const float*)d_in[11];
  const float* g_w     = (const float*)d_in[12];
  const float* o_norm_w= (const float*)d_in[13];
  const float* o_w     = (const float*)d_in[14];
  const float* norm2_w = (const float*)d_in[15];
  const float* gate_w  = (const float*)d_in[16];
  const float* up_w    = (const float*)d_in[17];
  const float* down_w  = (const float*)d_in[18];
  char* wsb = (char*)d_ws;
  float* out = (float*)d_out;

  bf16*  hbf  = (bf16*)(wsb + WO_HBF);    // h_bf, later h2_bf
  float* qkv  = (float*)(wsb + WO_QKV);
  bf16*  attn = (bf16*)(wsb + WO_QKV);    // after scan
  bf16*  actb = (bf16*)(wsb + WO_QKV);    // mlp activation
  float* gate = (float*)(wsb + WO_GATE);
  float* osc  = (float*)(wsb + WO_OSC);
  float* x1   = (float*)(wsb + WO_OSC);   // after gatednorm
  float* ba   = (float*)(wsb + WO_BA);
  bf16*  wb   = (bf16*)(wsb + WO_WB);

  dim3 tb(32, 8);
  // 0. transpose-cast weights to bf16 [N][K]
  tcast_k<<<dim3(24, 32), tb, 0, stream>>>(q_w,    wb + WB_QKVT,              1024, 768);
  tcast_k<<<dim3(24, 32), tb, 0, stream>>>(k_w,    wb + WB_QKVT + 768 * 1024, 1024, 768);
  tcast_k<<<dim3(48, 32), tb, 0, stream>>>(v_w,    wb + WB_QKVT + 1536 * 1024,1024, 1536);
  tcast_k<<<dim3(48, 32), tb, 0, stream>>>(g_w,    wb + WB_GT,                1024, 1536);
  tcast_k<<<dim3(32, 48), tb, 0, stream>>>(o_w,    wb + WB_OT,                1536, 1024);
  tcast_k<<<dim3(96, 32), tb, 0, stream>>>(gate_w, wb + WB_GATET,             1024, 3072);
  tcast_k<<<dim3(96, 32), tb, 0, stream>>>(up_w,   wb + WB_UPT,               1024, 3072);
  tcast_k<<<dim3(32, 96), tb, 0, stream>>>(down_w, wb + WB_DOWNT,             3072, 1024);
  tcast_k<<<dim3(1, 32),  tb, 0, stream>>>(b_w,    wb + WB_ABT,               1024, 16);
  tcast_k<<<dim3(1, 32),  tb, 0, stream>>>(a_w,    wb + WB_ABT + 16 * 1024,   1024, 16);

  // 1. h_bf = rmsnorm(x, norm1_w)
  rmsnorm_bf_k<<<BT, 256, 0, stream>>>(x, norm1_w, hbf);

  // 2. qkv = h @ [q|k|v]  (fp32 out)
  gemm_mfma<<<dim3(24, 64), 256, 0, stream>>>(hbf, wb + WB_QKVT, qkv, nullptr, 3072, 1024, 3072, 0);
  // 3. ba = h @ [b|a]  (N=32 guarded)
  gemm_mfma<<<dim3(1, 64), 256, 0, stream>>>(hbf, wb + WB_ABT, ba, nullptr, 32, 1024, 32, 0);
  // 4. gate = h @ g_w
  gemm_mfma<<<dim3(12, 64), 256, 0, stream>>>(hbf, wb + WB_GT, gate, nullptr, 1536, 1024, 1536, 0);

  // 5. causal conv + silu in place
  convsilu_k<<<(Bn * QKVC) / 256, 256, 0, stream>>>(qkv, cq_w, ck_w, cv_w);
  // 6. l2norm q,k
  l2norm_k<<<(BT * 32) / 4, 256, 0, stream>>>(qkv);
  // 7. beta/g transform
  betag_k<<<(BT * Hn) / 256, 256, 0, stream>>>(ba, A_log, dt_bias);
  // 8. gated delta rule scan
  scan2_k<<<Bn * Hn * 2, 64, 0, stream>>>(qkv, ba, osc);
  // 9. gated RMSNorm -> attn bf16 (into qkv region)
  gatednorm_bf_k<<<(BT * Hn) / 4, 256, 0, stream>>>(osc, gate, o_norm_w, attn);
  // 10. x1 = x + attn @ o_w
  gemm_mfma<<<dim3(8, 64), 256, 0, stream>>>(attn, wb + WB_OT, x1, x, 1024, 1536, 1024, 0);
  // 11. h2_bf = rmsnorm(x1)
  rmsnorm_bf_k<<<BT, 256, 0, stream>>>(x1, norm2_w, hbf);
  // 12. act = silu(h2@gate_w); act *= h2@up_w  (bf16, fused epilogues)
  gemm_mfma<<<dim3(24, 64), 256, 0, stream>>>(hbf, wb + WB_GATET, actb, nullptr, 3072, 1024, 3072, 1);
  gemm_mfma<<<dim3(24, 64), 256, 0, stream>>>(hbf, wb + WB_UPT, actb, nullptr, 3072, 1024, 3072, 2);
  // 13. out = x1 + act @ down_w
  gemm_mfma<<<dim3(8, 64), 256, 0, stream>>>(actb, wb + WB_DOWNT, out, x1, 1024, 3072, 1024, 0);
}

// Round 4
// 1269.214 us; speedup vs baseline: 6.1516x; 2.5944x over previous
//
#include <hip/hip_runtime.h>
#include <hip/hip_bf16.h>
#include <math.h>

// Problem constants
constexpr int Bn = 4, Tn = 2048, Dn = 1024, Hn = 16, DKn = 48, DVn = 96, In = 3072;
constexpr int BT = Bn * Tn;               // 8192
constexpr int HDK = Hn * DKn;             // 768
constexpr int HDV = Hn * DVn;             // 1536
constexpr int QKVC = 2 * HDK + HDV;       // 3072
constexpr int CC = 64;                    // chunk length
constexpr int NC = Tn / CC;               // 32 chunks per (b,h)

using bf16 = __hip_bfloat16;
typedef __attribute__((ext_vector_type(8))) short bf16x8;
typedef __attribute__((ext_vector_type(4))) float f32x4;

// ---- Workspace layout (byte offsets), total ~222.8 MB ----
constexpr size_t WO_HBF  = 0;              // h/h2 bf16 [8192][1024]        16 MB
constexpr size_t WO_QKV  = 16777216;       // qkv bf16 [8192][3072] 48MB; later attn bf16 / act bf16
constexpr size_t WO_GATE = 67108864;       // gate bf16 [8192][1536]        24 MB
constexpr size_t WO_OSC  = 92274688;       // osc fp32 [8192][1536] 48MB; later x1 fp32 32MB
constexpr size_t WO_BA   = 142606336;      // ba fp32 [8192][32]            1 MB
constexpr size_t WO_GC   = 143654912;      // Gc fp32 [64][2048]            0.5 MB
constexpr size_t WO_T    = 144703488;      // T bf16 [2048][64][64]         16.8 MB
constexpr size_t WO_UV   = 162529280;      // Uv bf16 [2048][64][96]        25.2 MB
constexpr size_t WO_WB   = 189792256;      // bf16 weights ~31.5 MB
// bf16-element offsets inside WB:
constexpr size_t WB_QKVT = 0;              // [3072][1024]
constexpr size_t WB_GT   = 3145728;        // [1536][1024]
constexpr size_t WB_OT   = 4718592;        // [1024][1536]
constexpr size_t WB_GATET= 6291456;        // [3072][1024]
constexpr size_t WB_UPT  = 9437184;        // [3072][1024]
constexpr size_t WB_DOWNT= 12582912;       // [1024][3072]
constexpr size_t WB_ABT  = 15728640;       // [32][1024]

__device__ __forceinline__ float sigmoidf_(float x) { return 1.f / (1.f + __expf(-x)); }
__device__ __forceinline__ float siluf(float x) { return x * sigmoidf_(x); }

__device__ __forceinline__ void glds16(const void* g, void* l) {
  __builtin_amdgcn_global_load_lds((const __attribute__((address_space(1))) void*)g,
                                   (__attribute__((address_space(3))) void*)l, 16, 0, 0);
}

__device__ __forceinline__ f32x4 mfma16(bf16x8 a, bf16x8 b, f32x4 c) {
  return __builtin_amdgcn_mfma_f32_16x16x32_bf16(a, b, c, 0, 0, 0);
}

// ---------------- transpose-cast: in fp32 [R][C] -> out bf16 [C][R] ----------------
__global__ void tcast_k(const float* __restrict__ in, bf16* __restrict__ out, int R, int C) {
  __shared__ float t[32][33];
  int tx = threadIdx.x, ty = threadIdx.y;
  int c0 = blockIdx.x * 32, r0 = blockIdx.y * 32;
#pragma unroll
  for (int j = 0; j < 4; j++) {
    int r = ty + j * 8;
    float v = (c0 + tx < C) ? in[(size_t)(r0 + r) * C + c0 + tx] : 0.f;
    t[r][tx] = v;
  }
  __syncthreads();
#pragma unroll
  for (int j = 0; j < 4; j++) {
    int cc = ty + j * 8;
    if (c0 + cc < C) out[(size_t)(c0 + cc) * R + r0 + tx] = __float2bfloat16(t[tx][cc]);
  }
}

// ---------------- RMSNorm -> bf16 out ----------------
__global__ void rmsnorm_bf_k(const float* __restrict__ x, const float* __restrict__ w,
                             bf16* __restrict__ y) {
  int row = blockIdx.x;
  const float4* xr = (const float4*)(x + (size_t)row * Dn);
  int tid = threadIdx.x;
  float4 v = xr[tid];
  float ss = v.x * v.x + v.y * v.y + v.z * v.z + v.w * v.w;
  for (int m = 32; m >= 1; m >>= 1) ss += __shfl_xor(ss, m, 64);
  __shared__ float wsum[4];
  if ((tid & 63) == 0) wsum[tid >> 6] = ss;
  __syncthreads();
  ss = wsum[0] + wsum[1] + wsum[2] + wsum[3];
  float rs = rsqrtf(ss * (1.f / Dn) + 1e-5f);
  float4 wv = ((const float4*)w)[tid];
  bf16* yr = y + (size_t)row * Dn + tid * 4;
  yr[0] = __float2bfloat16(v.x * rs * wv.x);
  yr[1] = __float2bfloat16(v.y * rs * wv.y);
  yr[2] = __float2bfloat16(v.z * rs * wv.z);
  yr[3] = __float2bfloat16(v.w * rs * wv.w);
}

// ---------------- MFMA bf16 GEMM: C[8192,N] = A[8192,K] @ Bt[N,K]^T ----------------
// mode 0: fp32 out (+res). mode 1: bf16 silu(acc). mode 2: bf16 C_old*acc. mode 3: bf16 acc.
__global__ __launch_bounds__(256) void gemm_mfma(
    const bf16* __restrict__ A, const bf16* __restrict__ Bt,
    void* __restrict__ Cv, const float* __restrict__ res,
    int N, int K, int ldc, int mode) {
  __shared__ bf16 As[128 * 32];
  __shared__ bf16 Bs[128 * 32];
  int tid = threadIdx.x, lane = tid & 63, w = tid >> 6;
  int bm = blockIdx.y * 128, bn = blockIdx.x * 128;
  int wr = w >> 1, wc = w & 1;
  int srow = lane >> 2;
  int gq = (lane & 3) ^ ((lane >> 3) & 3);
  int qa = (lane >> 4) ^ ((lane >> 1) & 3);
  int arow_base = wr * 64 + (lane & 15);
  int brow_base = wc * 64 + (lane & 15);
  f32x4 acc[4][4];
#pragma unroll
  for (int m = 0; m < 4; m++)
#pragma unroll
    for (int n = 0; n < 4; n++) acc[m][n] = (f32x4){0.f, 0.f, 0.f, 0.f};

  for (int k0 = 0; k0 < K; k0 += 32) {
#pragma unroll
    for (int cc = 0; cc < 2; cc++) {
      int c = 2 * w + cc;
      int arow = bm + c * 16 + srow;
      glds16(A + (size_t)arow * K + k0 + gq * 8, &As[c * 512]);
      int brow = bn + c * 16 + srow; if (brow >= N) brow = 0;
      glds16(Bt + (size_t)brow * K + k0 + gq * 8, &Bs[c * 512]);
    }
    __syncthreads();
    bf16x8 af[4], bfr[4];
#pragma unroll
    for (int m = 0; m < 4; m++) {
      int r = arow_base + m * 16;
      af[m] = *(const bf16x8*)&As[r * 32 + qa * 8];
    }
#pragma unroll
    for (int n = 0; n < 4; n++) {
      int r = brow_base + n * 16;
      bfr[n] = *(const bf16x8*)&Bs[r * 32 + qa * 8];
    }
#pragma unroll
    for (int m = 0; m < 4; m++)
#pragma unroll
      for (int n = 0; n < 4; n++)
        acc[m][n] = mfma16(af[m], bfr[n], acc[m][n]);
    __syncthreads();
  }
#pragma unroll
  for (int m = 0; m < 4; m++) {
#pragma unroll
    for (int n = 0; n < 4; n++) {
      int col = bn + wc * 64 + n * 16 + (lane & 15);
      if (col >= N) continue;
#pragma unroll
      for (int i = 0; i < 4; i++) {
        int row = bm + wr * 64 + m * 16 + (lane >> 4) * 4 + i;
        float v = acc[m][n][i];
        size_t idx = (size_t)row * ldc + col;
        if (mode == 0) {
          if (res) v += res[idx];
          ((float*)Cv)[idx] = v;
        } else if (mode == 1) {
          ((bf16*)Cv)[idx] = __float2bfloat16(siluf(v));
        } else if (mode == 2) {
          bf16* Cp = (bf16*)Cv;
          float old = __bfloat162float(Cp[idx]);
          Cp[idx] = __float2bfloat16(old * v);
        } else {
          ((bf16*)Cv)[idx] = __float2bfloat16(v);
        }
      }
    }
  }
}

// ---------------- Causal depthwise conv (K=4) + silu, in place on bf16 [B,T,3072] ----------------
__global__ void convsilu_k(bf16* __restrict__ qkv, const float* __restrict__ wq,
                           const float* __restrict__ wk, const float* __restrict__ wv) {
  int gid = blockIdx.x * blockDim.x + threadIdx.x;
  int c = gid % QKVC, b = gid / QKVC;
  const float* w = (c < HDK) ? (wq + c * 4)
                   : (c < 2 * HDK) ? (wk + (c - HDK) * 4)
                                   : (wv + (c - 2 * HDK) * 4);
  float w0 = w[0], w1 = w[1], w2 = w[2], w3 = w[3];
  float x0 = 0.f, x1 = 0.f, x2 = 0.f;
  bf16* p = qkv + (size_t)b * Tn * QKVC + c;
  for (int t = 0; t < Tn; t++) {
    float xt = __bfloat162float(p[(size_t)t * QKVC]);
    float y = x0 * w0 + x1 * w1 + x2 * w2 + xt * w3;
    p[(size_t)t * QKVC] = __float2bfloat16(siluf(y));
    x0 = x1; x1 = x2; x2 = xt;
  }
}

// ---------------- l2norm over 48-element head rows of q,k (bf16 in place) ----------------
__global__ void l2norm_k(bf16* __restrict__ qkv) {
  int wid = (blockIdx.x * blockDim.x + threadIdx.x) >> 6;
  int lane = threadIdx.x & 63;
  int t = wid >> 5, hr = wid & 31;
  bf16* p = qkv + (size_t)t * QKVC + hr * DKn;
  float v = (lane < DKn) ? __bfloat162float(p[lane]) : 0.f;
  float ss = v * v;
  for (int m = 32; m >= 1; m >>= 1) ss += __shfl_xor(ss, m, 64);
  float rs = rsqrtf(ss + 1e-6f);
  if (lane < DKn) p[lane] = __float2bfloat16(v * rs);
}

// ---------------- beta = sigmoid(b), g = -exp(A_log)*softplus(a+dt_bias), in place ----------------
__global__ void betag_k(float* __restrict__ ba, const float* __restrict__ A_log,
                        const float* __restrict__ dt_bias) {
  int i = blockIdx.x * blockDim.x + threadIdx.x;
  int h = i & 15, r = i >> 4;
  float bv = ba[(size_t)r * 32 + h];
  float av = ba[(size_t)r * 32 + 16 + h];
  ba[(size_t)r * 32 + h] = sigmoidf_(bv);
  float xx = av + dt_bias[h];
  float sp = (xx > 20.f) ? xx : log1pf(__expf(xx));
  ba[(size_t)r * 32 + 16 + h] = -__expf(A_log[h]) * sp;
}

// ---------------- P1: per-chunk WY precompute (parallel over b,h,chunk) ----------------
// Computes Gc (in-chunk inclusive cumsum of g), D=KK^T, N[t][s]=beta_t*exp(Gc_t-Gc_s)*D (s<t),
// then forward-substitutes (I+N)^{-1} applied to [I | beta*V] with RHS columns in registers.
__global__ __launch_bounds__(256) void dn_p1(const bf16* __restrict__ qkv,
                                             const float* __restrict__ ba,
                                             float* __restrict__ Gc_g,
                                             bf16* __restrict__ T_g,
                                             bf16* __restrict__ Uv_g) {
  __shared__ bf16 Kl[64][72];
  __shared__ bf16 Vl[64][100];
  __shared__ float Nl[64][68];
  __shared__ float Gcl[64], Bl[64];
  int cid = blockIdx.x;
  int nc = cid & (NC - 1);
  int bh = cid >> 5;
  int h = bh & 15, b = bh >> 4;
  int t0 = nc * CC;
  int tid = threadIdx.x, lane = tid & 63, w = tid >> 6;
  // loads
  {
    int t = tid >> 2, p = tid & 3;
    const bf16* row = qkv + ((size_t)(b * Tn + t0 + t)) * QKVC;
    int c0 = p * 12;
#pragma unroll
    for (int j = 0; j < 12; ++j) Kl[t][c0 + j] = row[HDK + h * DKn + c0 + j];
    int j0 = p * 24;
#pragma unroll
    for (int j = 0; j < 24; ++j) Vl[t][j0 + j] = row[2 * HDK + h * DVn + j0 + j];
  }
  for (int i = tid; i < 64 * 24; i += 256) {  // zero pad cols 48..71
    int t = i / 24, c = 48 + (i % 24);
    Kl[t][c] = __float2bfloat16(0.f);
  }
  if (tid < 64) {
    size_t row = (size_t)(b * Tn + t0 + tid);
    float g = ba[row * 32 + 16 + h];
    float be = ba[row * 32 + h];
    float acc = g;
#pragma unroll
    for (int d = 1; d < 64; d <<= 1) {
      float o = __shfl_up(acc, d);
      if (tid >= d) acc += o;
    }
    Gcl[tid] = acc; Bl[tid] = be;
    Gc_g[(size_t)bh * Tn + t0 + tid] = acc;
  }
  __syncthreads();
  // D = K @ K^T
  f32x4 dacc[4];
#pragma unroll
  for (int n = 0; n < 4; n++) dacc[n] = (f32x4){0.f, 0.f, 0.f, 0.f};
  {
    int arow = w * 16 + (lane & 15);
    int qd = lane >> 4;
    bf16x8 a0 = *(const bf16x8*)&Kl[arow][qd * 8];
    bf16x8 a1 = *(const bf16x8*)&Kl[arow][32 + qd * 8];
#pragma unroll
    for (int n = 0; n < 4; n++) {
      int brow = n * 16 + (lane & 15);
      bf16x8 b0 = *(const bf16x8*)&Kl[brow][qd * 8];
      bf16x8 b1 = *(const bf16x8*)&Kl[brow][32 + qd * 8];
      dacc[n] = mfma16(a0, b0, dacc[n]);
      dacc[n] = mfma16(a1, b1, dacc[n]);
    }
  }
#pragma unroll
  for (int i = 0; i < 4; i++) {
    int t = w * 16 + (lane >> 4) * 4 + i;
    float bt = Bl[t], gt = Gcl[t];
#pragma unroll
    for (int n = 0; n < 4; n++) {
      int s = n * 16 + (lane & 15);
      Nl[t][s] = (s < t) ? bt * __expf(gt - Gcl[s]) * dacc[n][i] : 0.f;
    }
  }
  __syncthreads();
  // forward substitution, columns in registers (no syncs needed)
  int c = tid;
  if (c < 160) {
    float R[64];
    if (c < 64) {
#pragma unroll
      for (int t = 0; t < 64; ++t) R[t] = (t == c) ? 1.f : 0.f;
    } else {
      int j = c - 64;
#pragma unroll
      for (int t = 0; t < 64; ++t) R[t] = Bl[t] * __bfloat162float(Vl[t][j]);
    }
#pragma unroll
    for (int t = 1; t < 64; ++t) {
      float a0 = 0.f, a1 = 0.f, a2 = 0.f, a3 = 0.f;
#pragma unroll
      for (int s = 0; s + 3 < t; s += 4) {
        float4 n4 = *(const float4*)&Nl[t][s];
        a0 += n4.x * R[s]; a1 += n4.y * R[s + 1];
        a2 += n4.z * R[s + 2]; a3 += n4.w * R[s + 3];
      }
#pragma unroll
      for (int s = t & ~3; s < t; ++s) a0 += Nl[t][s] * R[s];
      R[t] -= ((a0 + a1) + (a2 + a3));
    }
    if (c < 64) {
#pragma unroll
      for (int t = 0; t < 64; ++t)
        T_g[(size_t)cid * 4096 + t * 64 + c] = __float2bfloat16(R[t]);
    } else {
      int j = c - 64;
#pragma unroll
      for (int t = 0; t < 64; ++t)
        Uv_g[(size_t)cid * 6144 + t * 96 + j] = __float2bfloat16(R[t]);
    }
  }
}

// ---------------- P2: serial inter-chunk recurrence, all-MFMA (64 blocks) ----------------
__global__ __launch_bounds__(256) void dn_p2(const bf16* __restrict__ qkv,
                                             const float* __restrict__ ba,
                                             const float* __restrict__ Gc_g,
                                             const bf16* __restrict__ T_g,
                                             const bf16* __restrict__ Uv_g,
                                             float* __restrict__ osc) {
  __shared__ bf16 Kl[64][72], KTl[64][72], Ql[64][72], QLl[64][72], Tl[64][72], Ml[64][72];
  __shared__ bf16 G1T[96][72], UT[96][72], UdT[96][72], STb[96][72];
  __shared__ float Gcl[64], Bl[64];
  int bh = blockIdx.x;
  int h = bh & 15, b = bh >> 4;
  int tid = threadIdx.x, lane = tid & 63, w = tid >> 6;
  int l15 = lane & 15, qd = lane >> 4;
  const float scale = 0.14433756729740643f;  // 48^-0.5
  bf16 zb = __float2bfloat16(0.f);
  f32x4 Sacc[6];
#pragma unroll
  for (int r = 0; r < 6; r++) Sacc[r] = (f32x4){0.f, 0.f, 0.f, 0.f};
  for (int i = tid; i < 96 * 72; i += 256) (&STb[0][0])[i] = zb;

  for (int nc = 0; nc < NC; ++nc) {
    int t0 = nc * CC;
    size_t cid = (size_t)bh * NC + nc;
    // loads
    {
      int t = tid >> 2, p = tid & 3;
      size_t grow = (size_t)(b * Tn + t0 + t);
      const bf16* row = qkv + grow * QKVC;
      float gc = Gc_g[(size_t)bh * Tn + t0 + t];
      float lam = __expf(gc);
      int c0 = p * 12;
#pragma unroll
      for (int j = 0; j < 12; ++j) {
        int cc = c0 + j;
        Kl[t][cc] = row[HDK + h * DKn + cc];
        float qv = __bfloat162float(row[h * DKn + cc]) * scale;
        Ql[t][cc] = __float2bfloat16(qv);
        QLl[t][cc] = __float2bfloat16(qv * lam);
      }
      if (p == 0) { Gcl[t] = gc; Bl[t] = ba[grow * 32 + h]; }
    }
    for (int i = tid; i < 64 * 16; i += 256) {
      int t = i >> 4, cc = 48 + (i & 15);
      Kl[t][cc] = zb; Ql[t][cc] = zb; QLl[t][cc] = zb;
    }
    for (int i = tid; i < 4096; i += 256) {
      int t = i >> 6, s = i & 63;
      Tl[t][s] = T_g[cid * 4096 + i];
    }
    __syncthreads();  // sync1
    for (int i = tid; i < 4096; i += 256) {
      int dk = i >> 6, t = i & 63;
      KTl[dk][t] = (dk < DKn) ? Kl[t][dk] : zb;
    }
    __syncthreads();  // sync2
    // (i) G1 = K @ S^T  -> G1T scaled by beta*lambda
    f32x4 acc[6];
#pragma unroll
    for (int n = 0; n < 6; n++) acc[n] = (f32x4){0.f, 0.f, 0.f, 0.f};
    {
      int arow = w * 16 + l15;
      bf16x8 a0 = *(const bf16x8*)&Kl[arow][qd * 8];
      bf16x8 a1 = *(const bf16x8*)&Kl[arow][32 + qd * 8];
#pragma unroll
      for (int n = 0; n < 6; n++) {
        int brow = n * 16 + l15;
        bf16x8 b0 = *(const bf16x8*)&STb[brow][qd * 8];
        bf16x8 b1 = *(const bf16x8*)&STb[brow][32 + qd * 8];
        acc[n] = mfma16(a0, b0, acc[n]);
        acc[n] = mfma16(a1, b1, acc[n]);
      }
    }
#pragma unroll
    for (int i = 0; i < 4; i++) {
      int tt = w * 16 + qd * 4 + i;
      float sc = Bl[tt] * __expf(Gcl[tt]);
#pragma unroll
      for (int n = 0; n < 6; n++) {
        int dv = n * 16 + l15;
        G1T[dv][tt] = __float2bfloat16(acc[n][i] * sc);
      }
    }
    __syncthreads();  // sync3
    // (ii) G2 = T @ G1 ; U = Uv - G2 -> UT, UdT
#pragma unroll
    for (int n = 0; n < 6; n++) acc[n] = (f32x4){0.f, 0.f, 0.f, 0.f};
    {
      int arow = w * 16 + l15;
      bf16x8 a0 = *(const bf16x8*)&Tl[arow][qd * 8];
      bf16x8 a1 = *(const bf16x8*)&Tl[arow][32 + qd * 8];
#pragma unroll
      for (int n = 0; n < 6; n++) {
        int brow = n * 16 + l15;
        bf16x8 b0 = *(const bf16x8*)&G1T[brow][qd * 8];
        bf16x8 b1 = *(const bf16x8*)&G1T[brow][32 + qd * 8];
        acc[n] = mfma16(a0, b0, acc[n]);
        acc[n] = mfma16(a1, b1, acc[n]);
      }
    }
#pragma unroll
    for (int i = 0; i < 4; i++) {
      int tt = w * 16 + qd * 4 + i;
      float edec = __expf(Gcl[63] - Gcl[tt]);
#pragma unroll
      for (int n = 0; n < 6; n++) {
        int dv = n * 16 + l15;
        float uv = __bfloat162float(Uv_g[cid * 6144 + tt * 96 + dv]);
        float u = uv - acc[n][i];
        UT[dv][tt] = __float2bfloat16(u);
        UdT[dv][tt] = __float2bfloat16(u * edec);
      }
    }
    __syncthreads();  // sync4
    // (iv) QK -> M (decay-scaled, causal inclusive)
    f32x4 qk[4];
#pragma unroll
    for (int n = 0; n < 4; n++) qk[n] = (f32x4){0.f, 0.f, 0.f, 0.f};
    {
      int arow = w * 16 + l15;
      bf16x8 a0 = *(const bf16x8*)&Ql[arow][qd * 8];
      bf16x8 a1 = *(const bf16x8*)&Ql[arow][32 + qd * 8];
#pragma unroll
      for (int n = 0; n < 4; n++) {
        int brow = n * 16 + l15;
        bf16x8 b0 = *(const bf16x8*)&Kl[brow][qd * 8];
        bf16x8 b1 = *(const bf16x8*)&Kl[brow][32 + qd * 8];
        qk[n] = mfma16(a0, b0, qk[n]);
        qk[n] = mfma16(a1, b1, qk[n]);
      }
    }
#pragma unroll
    for (int i = 0; i < 4; i++) {
      int tt = w * 16 + qd * 4 + i;
      float gt = Gcl[tt];
#pragma unroll
      for (int n = 0; n < 4; n++) {
        int ss = n * 16 + l15;
        float m = (ss <= tt) ? qk[n][i] * __expf(gt - Gcl[ss]) : 0.f;
        Ml[tt][ss] = __float2bfloat16(m);
      }
    }
    __syncthreads();  // sync5
    // (iii) Qlam @ S^T + (v) M @ U  -> o ; (vi) S = lamC*S + Ud^T @ K
#pragma unroll
    for (int n = 0; n < 6; n++) acc[n] = (f32x4){0.f, 0.f, 0.f, 0.f};
    {
      int arow = w * 16 + l15;
      bf16x8 a0 = *(const bf16x8*)&QLl[arow][qd * 8];
      bf16x8 a1 = *(const bf16x8*)&QLl[arow][32 + qd * 8];
      bf16x8 m0 = *(const bf16x8*)&Ml[arow][qd * 8];
      bf16x8 m1 = *(const bf16x8*)&Ml[arow][32 + qd * 8];
#pragma unroll
      for (int n = 0; n < 6; n++) {
        int brow = n * 16 + l15;
        bf16x8 b0 = *(const bf16x8*)&STb[brow][qd * 8];
        bf16x8 b1 = *(const bf16x8*)&STb[brow][32 + qd * 8];
        acc[n] = mfma16(a0, b0, acc[n]);
        acc[n] = mfma16(a1, b1, acc[n]);
        bf16x8 u0 = *(const bf16x8*)&UT[brow][qd * 8];
        bf16x8 u1 = *(const bf16x8*)&UT[brow][32 + qd * 8];
        acc[n] = mfma16(m0, u0, acc[n]);
        acc[n] = mfma16(m1, u1, acc[n]);
      }
    }
#pragma unroll
    for (int i = 0; i < 4; i++) {
      int tt = w * 16 + qd * 4 + i;
      size_t orow = ((size_t)(b * Tn + t0 + tt)) * HDV + h * DVn;
#pragma unroll
      for (int n = 0; n < 6; n++) osc[orow + n * 16 + l15] = acc[n][i];
    }
    float lamC = __expf(Gcl[63]);
#pragma unroll
    for (int r = 0; r < 6; r++) Sacc[r] *= lamC;
    {
      int brow = w * 16 + l15;
      bf16x8 kb0 = *(const bf16x8*)&KTl[brow][qd * 8];
      bf16x8 kb1 = *(const bf16x8*)&KTl[brow][32 + qd * 8];
#pragma unroll
      for (int r = 0; r < 6; r++) {
        int arow = r * 16 + l15;
        bf16x8 a0 = *(const bf16x8*)&UdT[arow][qd * 8];
        bf16x8 a1 = *(const bf16x8*)&UdT[arow][32 + qd * 8];
        Sacc[r] = mfma16(a0, kb0, Sacc[r]);
        Sacc[r] = mfma16(a1, kb1, Sacc[r]);
      }
    }
    __syncthreads();  // sync6
#pragma unroll
    for (int r = 0; r < 6; r++)
#pragma unroll
      for (int i = 0; i < 4; i++) {
        int dv = r * 16 + qd * 4 + i;
        STb[dv][w * 16 + l15] = __float2bfloat16(Sacc[r][i]);
      }
  }
}

// ---------------- fused gated RMSNorm -> bf16 (gate is bf16) ----------------
__global__ void gatednorm_bf_k(const float* __restrict__ o, const bf16* __restrict__ gate,
                               const float* __restrict__ onw, bf16* __restrict__ attn) {
  int wid = (blockIdx.x * blockDim.x + threadIdx.x) >> 6;
  int lane = threadIdx.x & 63;
  const float* orow = o + (size_t)wid * DVn;
  const bf16* grow = gate + (size_t)wid * DVn;
  bf16* arow = attn + (size_t)wid * DVn;
  float v0 = orow[lane];
  float v1 = (lane < 32) ? orow[64 + lane] : 0.f;
  float ss = v0 * v0 + v1 * v1;
  for (int m = 32; m >= 1; m >>= 1) ss += __shfl_xor(ss, m, 64);
  float rs = rsqrtf(ss * (1.f / DVn) + 1e-5f);
  float g0 = __bfloat162float(grow[lane]);
  arow[lane] = __float2bfloat16(v0 * rs * onw[lane] * siluf(g0));
  if (lane < 32) {
    float g1 = __bfloat162float(grow[64 + lane]);
    arow[64 + lane] = __float2bfloat16(v1 * rs * onw[64 + lane] * siluf(g1));
  }
}

extern "C" void kernel_launch(void* const* d_in, const int* in_sizes, int n_in,
                              void* d_out, int out_size, void* d_ws, size_t ws_size,
                              hipStream_t stream) {
  const float* x       = (const float*)d_in[0];
  const float* norm1_w = (const float*)d_in[1];
  const float* q_w     = (const float*)d_in[2];
  const float* k_w     = (const float*)d_in[3];
  const float* v_w     = (const float*)d_in[4];
  const float* cq_w    = (const float*)d_in[5];
  const float* ck_w    = (const float*)d_in[6];
  const float* cv_w    = (const float*)d_in[7];
  const float* b_w     = (const float*)d_in[8];
  const float* a_w     = (const float*)d_in[9];
  const float* A_log   = (const float*)d_in[10];
  const float* dt_bias = (const float*)d_in[11];
  const float* g_w     = (const float*)d_in[12];
  const float* o_norm_w= (const float*)d_in[13];
  const float* o_w     = (const float*)d_in[14];
  const float* norm2_w = (const float*)d_in[15];
  const float* gate_w  = (const float*)d_in[16];
  const float* up_w    = (const float*)d_in[17];
  const float* down_w  = (const float*)d_in[18];
  char* wsb = (char*)d_ws;
  float* out = (float*)d_out;

  bf16*  hbf   = (bf16*)(wsb + WO_HBF);
  bf16*  qkvb  = (bf16*)(wsb + WO_QKV);
  bf16*  attn  = (bf16*)(wsb + WO_QKV);
  bf16*  actb  = (bf16*)(wsb + WO_QKV);
  bf16*  gateb = (bf16*)(wsb + WO_GATE);
  float* osc   = (float*)(wsb + WO_OSC);
  float* x1    = (float*)(wsb + WO_OSC);
  float* ba    = (float*)(wsb + WO_BA);
  float* Gc    = (float*)(wsb + WO_GC);
  bf16*  Tg    = (bf16*)(wsb + WO_T);
  bf16*  Uvg   = (bf16*)(wsb + WO_UV);
  bf16*  wb    = (bf16*)(wsb + WO_WB);

  dim3 tb(32, 8);
  // 0. transpose-cast weights to bf16 [N][K]
  tcast_k<<<dim3(24, 32), tb, 0, stream>>>(q_w,    wb + WB_QKVT,              1024, 768);
  tcast_k<<<dim3(24, 32), tb, 0, stream>>>(k_w,    wb + WB_QKVT + 768 * 1024, 1024, 768);
  tcast_k<<<dim3(48, 32), tb, 0, stream>>>(v_w,    wb + WB_QKVT + 1536 * 1024,1024, 1536);
  tcast_k<<<dim3(48, 32), tb, 0, stream>>>(g_w,    wb + WB_GT,                1024, 1536);
  tcast_k<<<dim3(32, 48), tb, 0, stream>>>(o_w,    wb + WB_OT,                1536, 1024);
  tcast_k<<<dim3(96, 32), tb, 0, stream>>>(gate_w, wb + WB_GATET,             1024, 3072);
  tcast_k<<<dim3(96, 32), tb, 0, stream>>>(up_w,   wb + WB_UPT,               1024, 3072);
  tcast_k<<<dim3(32, 96), tb, 0, stream>>>(down_w, wb + WB_DOWNT,             3072, 1024);
  tcast_k<<<dim3(1, 32),  tb, 0, stream>>>(b_w,    wb + WB_ABT,               1024, 16);
  tcast_k<<<dim3(1, 32),  tb, 0, stream>>>(a_w,    wb + WB_ABT + 16 * 1024,   1024, 16);

  // 1. h_bf = rmsnorm(x)
  rmsnorm_bf_k<<<BT, 256, 0, stream>>>(x, norm1_w, hbf);
  // 2. qkv (bf16 out), ba (fp32), gate (bf16)
  gemm_mfma<<<dim3(24, 64), 256, 0, stream>>>(hbf, wb + WB_QKVT, qkvb, nullptr, 3072, 1024, 3072, 3);
  gemm_mfma<<<dim3(1, 64), 256, 0, stream>>>(hbf, wb + WB_ABT, ba, nullptr, 32, 1024, 32, 0);
  gemm_mfma<<<dim3(12, 64), 256, 0, stream>>>(hbf, wb + WB_GT, gateb, nullptr, 1536, 1024, 1536, 3);
  // 3. conv+silu, l2norm, beta/g
  convsilu_k<<<(Bn * QKVC) / 256, 256, 0, stream>>>(qkvb, cq_w, ck_w, cv_w);
  l2norm_k<<<(BT * 32) / 4, 256, 0, stream>>>(qkvb);
  betag_k<<<(BT * Hn) / 256, 256, 0, stream>>>(ba, A_log, dt_bias);
  // 4. chunked gated delta rule
  dn_p1<<<Bn * Hn * NC, 256, 0, stream>>>(qkvb, ba, Gc, Tg, Uvg);
  dn_p2<<<Bn * Hn, 256, 0, stream>>>(qkvb, ba, Gc, Tg, Uvg, osc);
  // 5. gated RMSNorm -> attn (bf16, into qkv region)
  gatednorm_bf_k<<<(BT * Hn) / 4, 256, 0, stream>>>(osc, gateb, o_norm_w, attn);
  // 6. x1 = x + attn @ o_w
  gemm_mfma<<<dim3(8, 64), 256, 0, stream>>>(attn, wb + WB_OT, x1, x, 1024, 1536, 1024, 0);
  // 7. h2 = rmsnorm(x1)
  rmsnorm_bf_k<<<BT, 256, 0, stream>>>(x1, norm2_w, hbf);
  // 8. act = silu(h2@gate_w) * (h2@up_w)
  gemm_mfma<<<dim3(24, 64), 256, 0, stream>>>(hbf, wb + WB_GATET, actb, nullptr, 3072, 1024, 3072, 1);
  gemm_mfma<<<dim3(24, 64), 256, 0, stream>>>(hbf, wb + WB_UPT, actb, nullptr, 3072, 1024, 3072, 2);
  // 9. out = x1 + act @ down_w
  gemm_mfma<<<dim3(8, 64), 256, 0, stream>>>(actb, wb + WB_DOWNT, out, x1, 1024, 3072, 1024, 0);
}

// Round 5
// 982.239 us; speedup vs baseline: 7.9489x; 1.2922x over previous
//
#include <hip/hip_runtime.h>
#include <hip/hip_bf16.h>
#include <math.h>

// Problem constants
constexpr int Bn = 4, Tn = 2048, Dn = 1024, Hn = 16, DKn = 48, DVn = 96, In = 3072;
constexpr int BT = Bn * Tn;               // 8192
constexpr int HDK = Hn * DKn;             // 768
constexpr int HDV = Hn * DVn;             // 1536
constexpr int QKVC = 2 * HDK + HDV;       // 3072
constexpr int CC = 64;                    // chunk length
constexpr int NC = Tn / CC;               // 32 chunks per (b,h)

using bf16 = __hip_bfloat16;
typedef __attribute__((ext_vector_type(8))) short bf16x8;
typedef __attribute__((ext_vector_type(4))) float f32x4;

// ---- Workspace layout (byte offsets), total ~239.6 MB < 256 MiB ----
constexpr size_t WO_HBF   = 0;              // h/h2 bf16 [8192][1024]     16 MB
constexpr size_t WO_QKVR  = 16777216;       // raw qkv bf16 48MB; later: osc(24MB)+attn(24MB); later act(24MB)
constexpr size_t WO_OSC   = 16777216;       // osc bf16 [8192][1536]      24 MB (aliases raw qkv)
constexpr size_t WO_ATTN  = 41943040;       // attn bf16 [8192][1536]     24 MB
constexpr size_t WO_ACT   = 16777216;       // mlp act bf16 [8192][3072]  48 MB (aliases osc+attn, both dead)
constexpr size_t WO_QKVC  = 67108864;       // conv'd qkv bf16 [8192][3072] 48 MB
constexpr size_t WO_GATE  = 117440512;      // gate bf16 [8192][1536]     24 MB
constexpr size_t WO_X1    = 142606336;      // x1 fp32 [8192][1024]       32 MB
constexpr size_t WO_BA    = 176160768;      // ba fp32 [8192][32]         1 MB
constexpr size_t WO_GC    = 177209344;      // Gc fp32 [64][2048]         0.5 MB
constexpr size_t WO_T     = 177733632;      // T bf16 [2048][64][64]      16.8 MB
constexpr size_t WO_UV    = 194510848;      // Uv bf16 [2048][64][96]     25.2 MB
constexpr size_t WO_WB    = 219676672;      // bf16 weights ~31.5 MB
// bf16-element offsets inside WB:
constexpr size_t WB_QKVT = 0;              // [3072][1024]
constexpr size_t WB_GT   = 3145728;        // [1536][1024]
constexpr size_t WB_OT   = 4718592;        // [1024][1536]
constexpr size_t WB_GATET= 6291456;        // [3072][1024]
constexpr size_t WB_UPT  = 9437184;        // [3072][1024]
constexpr size_t WB_DOWNT= 12582912;       // [1024][3072]
constexpr size_t WB_ABT  = 15728640;       // [32][1024]

__device__ __forceinline__ float sigmoidf_(float x) { return 1.f / (1.f + __expf(-x)); }
__device__ __forceinline__ float siluf(float x) { return x * sigmoidf_(x); }

__device__ __forceinline__ void glds16(const void* g, void* l) {
  __builtin_amdgcn_global_load_lds((const __attribute__((address_space(1))) void*)g,
                                   (__attribute__((address_space(3))) void*)l, 16, 0, 0);
}

__device__ __forceinline__ f32x4 mfma16(bf16x8 a, bf16x8 b, f32x4 c) {
  return __builtin_amdgcn_mfma_f32_16x16x32_bf16(a, b, c, 0, 0, 0);
}

// ---------------- transpose-cast: in fp32 [R][C] -> out bf16 [C][R] ----------------
__global__ void tcast_k(const float* __restrict__ in, bf16* __restrict__ out, int R, int C) {
  __shared__ float t[32][33];
  int tx = threadIdx.x, ty = threadIdx.y;
  int c0 = blockIdx.x * 32, r0 = blockIdx.y * 32;
#pragma unroll
  for (int j = 0; j < 4; j++) {
    int r = ty + j * 8;
    float v = (c0 + tx < C) ? in[(size_t)(r0 + r) * C + c0 + tx] : 0.f;
    t[r][tx] = v;
  }
  __syncthreads();
#pragma unroll
  for (int j = 0; j < 4; j++) {
    int cc = ty + j * 8;
    if (c0 + cc < C) out[(size_t)(c0 + cc) * R + r0 + tx] = __float2bfloat16(t[tx][cc]);
  }
}

// ---------------- RMSNorm -> bf16 out ----------------
__global__ void rmsnorm_bf_k(const float* __restrict__ x, const float* __restrict__ w,
                             bf16* __restrict__ y) {
  int row = blockIdx.x;
  const float4* xr = (const float4*)(x + (size_t)row * Dn);
  int tid = threadIdx.x;
  float4 v = xr[tid];
  float ss = v.x * v.x + v.y * v.y + v.z * v.z + v.w * v.w;
  for (int m = 32; m >= 1; m >>= 1) ss += __shfl_xor(ss, m, 64);
  __shared__ float wsum[4];
  if ((tid & 63) == 0) wsum[tid >> 6] = ss;
  __syncthreads();
  ss = wsum[0] + wsum[1] + wsum[2] + wsum[3];
  float rs = rsqrtf(ss * (1.f / Dn) + 1e-5f);
  float4 wv = ((const float4*)w)[tid];
  bf16* yr = y + (size_t)row * Dn + tid * 4;
  yr[0] = __float2bfloat16(v.x * rs * wv.x);
  yr[1] = __float2bfloat16(v.y * rs * wv.y);
  yr[2] = __float2bfloat16(v.z * rs * wv.z);
  yr[3] = __float2bfloat16(v.w * rs * wv.w);
}

// ---------------- MFMA bf16 GEMM: C[8192,N] = A[8192,K] @ Bt[N,K]^T ----------------
// mode 0: fp32 out (+res). mode 1: bf16 silu(acc). mode 2: bf16 C_old*acc. mode 3: bf16 acc.
__global__ __launch_bounds__(256) void gemm_mfma(
    const bf16* __restrict__ A, const bf16* __restrict__ Bt,
    void* __restrict__ Cv, const float* __restrict__ res,
    int N, int K, int ldc, int mode) {
  __shared__ bf16 As[128 * 32];
  __shared__ bf16 Bs[128 * 32];
  int tid = threadIdx.x, lane = tid & 63, w = tid >> 6;
  int bm = blockIdx.y * 128, bn = blockIdx.x * 128;
  int wr = w >> 1, wc = w & 1;
  int srow = lane >> 2;
  int gq = (lane & 3) ^ ((lane >> 3) & 3);
  int qa = (lane >> 4) ^ ((lane >> 1) & 3);
  int arow_base = wr * 64 + (lane & 15);
  int brow_base = wc * 64 + (lane & 15);
  f32x4 acc[4][4];
#pragma unroll
  for (int m = 0; m < 4; m++)
#pragma unroll
    for (int n = 0; n < 4; n++) acc[m][n] = (f32x4){0.f, 0.f, 0.f, 0.f};

  for (int k0 = 0; k0 < K; k0 += 32) {
#pragma unroll
    for (int cc = 0; cc < 2; cc++) {
      int c = 2 * w + cc;
      int arow = bm + c * 16 + srow;
      glds16(A + (size_t)arow * K + k0 + gq * 8, &As[c * 512]);
      int brow = bn + c * 16 + srow; if (brow >= N) brow = 0;
      glds16(Bt + (size_t)brow * K + k0 + gq * 8, &Bs[c * 512]);
    }
    __syncthreads();
    bf16x8 af[4], bfr[4];
#pragma unroll
    for (int m = 0; m < 4; m++) {
      int r = arow_base + m * 16;
      af[m] = *(const bf16x8*)&As[r * 32 + qa * 8];
    }
#pragma unroll
    for (int n = 0; n < 4; n++) {
      int r = brow_base + n * 16;
      bfr[n] = *(const bf16x8*)&Bs[r * 32 + qa * 8];
    }
#pragma unroll
    for (int m = 0; m < 4; m++)
#pragma unroll
      for (int n = 0; n < 4; n++)
        acc[m][n] = mfma16(af[m], bfr[n], acc[m][n]);
    __syncthreads();
  }
#pragma unroll
  for (int m = 0; m < 4; m++) {
#pragma unroll
    for (int n = 0; n < 4; n++) {
      int col = bn + wc * 64 + n * 16 + (lane & 15);
      if (col >= N) continue;
#pragma unroll
      for (int i = 0; i < 4; i++) {
        int row = bm + wr * 64 + m * 16 + (lane >> 4) * 4 + i;
        float v = acc[m][n][i];
        size_t idx = (size_t)row * ldc + col;
        if (mode == 0) {
          if (res) v += res[idx];
          ((float*)Cv)[idx] = v;
        } else if (mode == 1) {
          ((bf16*)Cv)[idx] = __float2bfloat16(siluf(v));
        } else if (mode == 2) {
          bf16* Cp = (bf16*)Cv;
          float old = __bfloat162float(Cp[idx]);
          Cp[idx] = __float2bfloat16(old * v);
        } else {
          ((bf16*)Cv)[idx] = __float2bfloat16(v);
        }
      }
    }
  }
}

// ---------------- Parallel causal conv (K=4) + silu: in -> out (separate buffers) ----------------
// Thread = (token, 8 channels). 4 coalesced bf16x8 row loads; L2 absorbs the 4x overlap.
__global__ __launch_bounds__(256) void convsilu2_k(const bf16* __restrict__ in,
                                                   bf16* __restrict__ outp,
                                                   const float* __restrict__ wq,
                                                   const float* __restrict__ wk,
                                                   const float* __restrict__ wv) {
  int tx = threadIdx.x & 31;   // ch8 index within block
  int ty = threadIdx.x >> 5;   // token within block (0..7)
  int c = (blockIdx.x * 32 + tx) * 8;
  int gt = blockIdx.y * 8 + ty;
  int b = gt >> 11, t = gt & (Tn - 1);
  const float* wsrc = (c < HDK) ? (wq + c * 4)
                     : (c < 2 * HDK) ? (wk + (c - HDK) * 4)
                                     : (wv + (c - 2 * HDK) * 4);
  float4 W[8];
#pragma unroll
  for (int j = 0; j < 8; j++) W[j] = ((const float4*)wsrc)[j];
  const bf16* base = in + (size_t)b * Tn * QKVC + c;
  bf16x8 r[4];
  bf16x8 zero = {0, 0, 0, 0, 0, 0, 0, 0};
#pragma unroll
  for (int j = 0; j < 4; j++) {
    int tt = t - 3 + j;
    r[j] = (tt >= 0) ? *(const bf16x8*)(base + (size_t)tt * QKVC) : zero;
  }
  bf16x8 o;
#pragma unroll
  for (int ch = 0; ch < 8; ch++) {
    float x0 = __bfloat162float(__ushort_as_bfloat16((unsigned short)r[0][ch]));
    float x1 = __bfloat162float(__ushort_as_bfloat16((unsigned short)r[1][ch]));
    float x2 = __bfloat162float(__ushort_as_bfloat16((unsigned short)r[2][ch]));
    float x3 = __bfloat162float(__ushort_as_bfloat16((unsigned short)r[3][ch]));
    float y = x0 * W[ch].x + x1 * W[ch].y + x2 * W[ch].z + x3 * W[ch].w;
    o[ch] = (short)__bfloat16_as_ushort(__float2bfloat16(siluf(y)));
  }
  *(bf16x8*)(outp + (size_t)gt * QKVC + c) = o;
}

// ---------------- l2norm over 48-element head rows of q,k (bf16 in place) ----------------
__global__ void l2norm_k(bf16* __restrict__ qkv) {
  int wid = (blockIdx.x * blockDim.x + threadIdx.x) >> 6;
  int lane = threadIdx.x & 63;
  int t = wid >> 5, hr = wid & 31;
  bf16* p = qkv + (size_t)t * QKVC + hr * DKn;
  float v = (lane < DKn) ? __bfloat162float(p[lane]) : 0.f;
  float ss = v * v;
  for (int m = 32; m >= 1; m >>= 1) ss += __shfl_xor(ss, m, 64);
  float rs = rsqrtf(ss + 1e-6f);
  if (lane < DKn) p[lane] = __float2bfloat16(v * rs);
}

// ---------------- beta = sigmoid(b), g = -exp(A_log)*softplus(a+dt_bias), in place ----------------
__global__ void betag_k(float* __restrict__ ba, const float* __restrict__ A_log,
                        const float* __restrict__ dt_bias) {
  int i = blockIdx.x * blockDim.x + threadIdx.x;
  int h = i & 15, r = i >> 4;
  float bv = ba[(size_t)r * 32 + h];
  float av = ba[(size_t)r * 32 + 16 + h];
  ba[(size_t)r * 32 + h] = sigmoidf_(bv);
  float xx = av + dt_bias[h];
  float sp = (xx > 20.f) ? xx : log1pf(__expf(xx));
  ba[(size_t)r * 32 + 16 + h] = -__expf(A_log[h]) * sp;
}

// ---------------- P1: per-chunk WY precompute (parallel over b,h,chunk) ----------------
__global__ __launch_bounds__(256) void dn_p1(const bf16* __restrict__ qkv,
                                             const float* __restrict__ ba,
                                             float* __restrict__ Gc_g,
                                             bf16* __restrict__ T_g,
                                             bf16* __restrict__ Uv_g) {
  __shared__ bf16 Kl[64][72];
  __shared__ bf16 Vl[64][100];
  __shared__ float Nl[64][68];
  __shared__ float Gcl[64], Bl[64];
  int cid = blockIdx.x;
  int nc = cid & (NC - 1);
  int bh = cid >> 5;
  int h = bh & 15, b = bh >> 4;
  int t0 = nc * CC;
  int tid = threadIdx.x, lane = tid & 63, w = tid >> 6;
  {
    int t = tid >> 2, p = tid & 3;
    const bf16* row = qkv + ((size_t)(b * Tn + t0 + t)) * QKVC;
    int c0 = p * 12;
#pragma unroll
    for (int j = 0; j < 12; ++j) Kl[t][c0 + j] = row[HDK + h * DKn + c0 + j];
    int j0 = p * 24;
#pragma unroll
    for (int j = 0; j < 24; ++j) Vl[t][j0 + j] = row[2 * HDK + h * DVn + j0 + j];
  }
  for (int i = tid; i < 64 * 24; i += 256) {
    int t = i / 24, c = 48 + (i % 24);
    Kl[t][c] = __float2bfloat16(0.f);
  }
  if (tid < 64) {
    size_t row = (size_t)(b * Tn + t0 + tid);
    float g = ba[row * 32 + 16 + h];
    float be = ba[row * 32 + h];
    float acc = g;
#pragma unroll
    for (int d = 1; d < 64; d <<= 1) {
      float o = __shfl_up(acc, d);
      if (tid >= d) acc += o;
    }
    Gcl[tid] = acc; Bl[tid] = be;
    Gc_g[(size_t)bh * Tn + t0 + tid] = acc;
  }
  __syncthreads();
  f32x4 dacc[4];
#pragma unroll
  for (int n = 0; n < 4; n++) dacc[n] = (f32x4){0.f, 0.f, 0.f, 0.f};
  {
    int arow = w * 16 + (lane & 15);
    int qd = lane >> 4;
    bf16x8 a0 = *(const bf16x8*)&Kl[arow][qd * 8];
    bf16x8 a1 = *(const bf16x8*)&Kl[arow][32 + qd * 8];
#pragma unroll
    for (int n = 0; n < 4; n++) {
      int brow = n * 16 + (lane & 15);
      bf16x8 b0 = *(const bf16x8*)&Kl[brow][qd * 8];
      bf16x8 b1 = *(const bf16x8*)&Kl[brow][32 + qd * 8];
      dacc[n] = mfma16(a0, b0, dacc[n]);
      dacc[n] = mfma16(a1, b1, dacc[n]);
    }
  }
#pragma unroll
  for (int i = 0; i < 4; i++) {
    int t = w * 16 + (lane >> 4) * 4 + i;
    float bt = Bl[t], gt = Gcl[t];
#pragma unroll
    for (int n = 0; n < 4; n++) {
      int s = n * 16 + (lane & 15);
      Nl[t][s] = (s < t) ? bt * __expf(gt - Gcl[s]) * dacc[n][i] : 0.f;
    }
  }
  __syncthreads();
  int c = tid;
  if (c < 160) {
    float R[64];
    if (c < 64) {
#pragma unroll
      for (int t = 0; t < 64; ++t) R[t] = (t == c) ? 1.f : 0.f;
    } else {
      int j = c - 64;
#pragma unroll
      for (int t = 0; t < 64; ++t) R[t] = Bl[t] * __bfloat162float(Vl[t][j]);
    }
#pragma unroll
    for (int t = 1; t < 64; ++t) {
      float a0 = 0.f, a1 = 0.f, a2 = 0.f, a3 = 0.f;
#pragma unroll
      for (int s = 0; s + 3 < t; s += 4) {
        float4 n4 = *(const float4*)&Nl[t][s];
        a0 += n4.x * R[s]; a1 += n4.y * R[s + 1];
        a2 += n4.z * R[s + 2]; a3 += n4.w * R[s + 3];
      }
#pragma unroll
      for (int s = t & ~3; s < t; ++s) a0 += Nl[t][s] * R[s];
      R[t] -= ((a0 + a1) + (a2 + a3));
    }
    if (c < 64) {
#pragma unroll
      for (int t = 0; t < 64; ++t)
        T_g[(size_t)cid * 4096 + t * 64 + c] = __float2bfloat16(R[t]);
    } else {
      int j = c - 64;
#pragma unroll
      for (int t = 0; t < 64; ++t)
        Uv_g[(size_t)cid * 6144 + t * 96 + j] = __float2bfloat16(R[t]);
    }
  }
}

// ---------------- P2: serial inter-chunk recurrence, all-MFMA (64 blocks) ----------------
__global__ __launch_bounds__(256) void dn_p2(const bf16* __restrict__ qkv,
                                             const float* __restrict__ ba,
                                             const float* __restrict__ Gc_g,
                                             const bf16* __restrict__ T_g,
                                             const bf16* __restrict__ Uv_g,
                                             bf16* __restrict__ osc) {
  __shared__ bf16 Kl[64][72], KTl[64][72], Ql[64][72], QLl[64][72], Tl[64][72], Ml[64][72];
  __shared__ bf16 G1T[96][72], UT[96][72], UdT[96][72], STb[96][72];
  __shared__ float Gcl[64], Bl[64];
  int bh = blockIdx.x;
  int h = bh & 15, b = bh >> 4;
  int tid = threadIdx.x, lane = tid & 63, w = tid >> 6;
  int l15 = lane & 15, qd = lane >> 4;
  const float scale = 0.14433756729740643f;  // 48^-0.5
  bf16 zb = __float2bfloat16(0.f);
  f32x4 Sacc[6];
#pragma unroll
  for (int r = 0; r < 6; r++) Sacc[r] = (f32x4){0.f, 0.f, 0.f, 0.f};
  for (int i = tid; i < 96 * 72; i += 256) (&STb[0][0])[i] = zb;

  for (int nc = 0; nc < NC; ++nc) {
    int t0 = nc * CC;
    size_t cid = (size_t)bh * NC + nc;
    {
      int t = tid >> 2, p = tid & 3;
      size_t grow = (size_t)(b * Tn + t0 + t);
      const bf16* row = qkv + grow * QKVC;
      float gc = Gc_g[(size_t)bh * Tn + t0 + t];
      float lam = __expf(gc);
      int c0 = p * 12;
#pragma unroll
      for (int j = 0; j < 12; ++j) {
        int cc = c0 + j;
        Kl[t][cc] = row[HDK + h * DKn + cc];
        float qv = __bfloat162float(row[h * DKn + cc]) * scale;
        Ql[t][cc] = __float2bfloat16(qv);
        QLl[t][cc] = __float2bfloat16(qv * lam);
      }
      if (p == 0) { Gcl[t] = gc; Bl[t] = ba[grow * 32 + h]; }
    }
    for (int i = tid; i < 64 * 16; i += 256) {
      int t = i >> 4, cc = 48 + (i & 15);
      Kl[t][cc] = zb; Ql[t][cc] = zb; QLl[t][cc] = zb;
    }
    for (int i = tid; i < 4096; i += 256) {
      int t = i >> 6, s = i & 63;
      Tl[t][s] = T_g[cid * 4096 + i];
    }
    __syncthreads();  // sync1
    for (int i = tid; i < 4096; i += 256) {
      int dk = i >> 6, t = i & 63;
      KTl[dk][t] = (dk < DKn) ? Kl[t][dk] : zb;
    }
    __syncthreads();  // sync2
    // (i) G1 = K @ S^T  -> G1T scaled by beta*lambda
    f32x4 acc[6];
#pragma unroll
    for (int n = 0; n < 6; n++) acc[n] = (f32x4){0.f, 0.f, 0.f, 0.f};
    {
      int arow = w * 16 + l15;
      bf16x8 a0 = *(const bf16x8*)&Kl[arow][qd * 8];
      bf16x8 a1 = *(const bf16x8*)&Kl[arow][32 + qd * 8];
#pragma unroll
      for (int n = 0; n < 6; n++) {
        int brow = n * 16 + l15;
        bf16x8 b0 = *(const bf16x8*)&STb[brow][qd * 8];
        bf16x8 b1 = *(const bf16x8*)&STb[brow][32 + qd * 8];
        acc[n] = mfma16(a0, b0, acc[n]);
        acc[n] = mfma16(a1, b1, acc[n]);
      }
    }
#pragma unroll
    for (int i = 0; i < 4; i++) {
      int tt = w * 16 + qd * 4 + i;
      float sc = Bl[tt] * __expf(Gcl[tt]);
#pragma unroll
      for (int n = 0; n < 6; n++) {
        int dv = n * 16 + l15;
        G1T[dv][tt] = __float2bfloat16(acc[n][i] * sc);
      }
    }
    __syncthreads();  // sync3
    // (ii) G2 = T @ G1 ; U = Uv - G2 -> UT, UdT
#pragma unroll
    for (int n = 0; n < 6; n++) acc[n] = (f32x4){0.f, 0.f, 0.f, 0.f};
    {
      int arow = w * 16 + l15;
      bf16x8 a0 = *(const bf16x8*)&Tl[arow][qd * 8];
      bf16x8 a1 = *(const bf16x8*)&Tl[arow][32 + qd * 8];
#pragma unroll
      for (int n = 0; n < 6; n++) {
        int brow = n * 16 + l15;
        bf16x8 b0 = *(const bf16x8*)&G1T[brow][qd * 8];
        bf16x8 b1 = *(const bf16x8*)&G1T[brow][32 + qd * 8];
        acc[n] = mfma16(a0, b0, acc[n]);
        acc[n] = mfma16(a1, b1, acc[n]);
      }
    }
#pragma unroll
    for (int i = 0; i < 4; i++) {
      int tt = w * 16 + qd * 4 + i;
      float edec = __expf(Gcl[63] - Gcl[tt]);
#pragma unroll
      for (int n = 0; n < 6; n++) {
        int dv = n * 16 + l15;
        float uv = __bfloat162float(Uv_g[cid * 6144 + tt * 96 + dv]);
        float u = uv - acc[n][i];
        UT[dv][tt] = __float2bfloat16(u);
        UdT[dv][tt] = __float2bfloat16(u * edec);
      }
    }
    __syncthreads();  // sync4
    // (iv) QK -> M (decay-scaled, causal inclusive)
    f32x4 qk[4];
#pragma unroll
    for (int n = 0; n < 4; n++) qk[n] = (f32x4){0.f, 0.f, 0.f, 0.f};
    {
      int arow = w * 16 + l15;
      bf16x8 a0 = *(const bf16x8*)&Ql[arow][qd * 8];
      bf16x8 a1 = *(const bf16x8*)&Ql[arow][32 + qd * 8];
#pragma unroll
      for (int n = 0; n < 4; n++) {
        int brow = n * 16 + l15;
        bf16x8 b0 = *(const bf16x8*)&Kl[brow][qd * 8];
        bf16x8 b1 = *(const bf16x8*)&Kl[brow][32 + qd * 8];
        qk[n] = mfma16(a0, b0, qk[n]);
        qk[n] = mfma16(a1, b1, qk[n]);
      }
    }
#pragma unroll
    for (int i = 0; i < 4; i++) {
      int tt = w * 16 + qd * 4 + i;
      float gt = Gcl[tt];
#pragma unroll
      for (int n = 0; n < 4; n++) {
        int ss = n * 16 + l15;
        float m = (ss <= tt) ? qk[n][i] * __expf(gt - Gcl[ss]) : 0.f;
        Ml[tt][ss] = __float2bfloat16(m);
      }
    }
    __syncthreads();  // sync5
    // (iii) Qlam @ S^T + (v) M @ U  -> o ; (vi) S = lamC*S + Ud^T @ K
#pragma unroll
    for (int n = 0; n < 6; n++) acc[n] = (f32x4){0.f, 0.f, 0.f, 0.f};
    {
      int arow = w * 16 + l15;
      bf16x8 a0 = *(const bf16x8*)&QLl[arow][qd * 8];
      bf16x8 a1 = *(const bf16x8*)&QLl[arow][32 + qd * 8];
      bf16x8 m0 = *(const bf16x8*)&Ml[arow][qd * 8];
      bf16x8 m1 = *(const bf16x8*)&Ml[arow][32 + qd * 8];
#pragma unroll
      for (int n = 0; n < 6; n++) {
        int brow = n * 16 + l15;
        bf16x8 b0 = *(const bf16x8*)&STb[brow][qd * 8];
        bf16x8 b1 = *(const bf16x8*)&STb[brow][32 + qd * 8];
        acc[n] = mfma16(a0, b0, acc[n]);
        acc[n] = mfma16(a1, b1, acc[n]);
        bf16x8 u0 = *(const bf16x8*)&UT[brow][qd * 8];
        bf16x8 u1 = *(const bf16x8*)&UT[brow][32 + qd * 8];
        acc[n] = mfma16(m0, u0, acc[n]);
        acc[n] = mfma16(m1, u1, acc[n]);
      }
    }
#pragma unroll
    for (int i = 0; i < 4; i++) {
      int tt = w * 16 + qd * 4 + i;
      size_t orow = ((size_t)(b * Tn + t0 + tt)) * HDV + h * DVn;
#pragma unroll
      for (int n = 0; n < 6; n++)
        osc[orow + n * 16 + l15] = __float2bfloat16(acc[n][i]);
    }
    float lamC = __expf(Gcl[63]);
#pragma unroll
    for (int r = 0; r < 6; r++) Sacc[r] *= lamC;
    {
      int brow = w * 16 + l15;
      bf16x8 kb0 = *(const bf16x8*)&KTl[brow][qd * 8];
      bf16x8 kb1 = *(const bf16x8*)&KTl[brow][32 + qd * 8];
#pragma unroll
      for (int r = 0; r < 6; r++) {
        int arow = r * 16 + l15;
        bf16x8 a0 = *(const bf16x8*)&UdT[arow][qd * 8];
        bf16x8 a1 = *(const bf16x8*)&UdT[arow][32 + qd * 8];
        Sacc[r] = mfma16(a0, kb0, Sacc[r]);
        Sacc[r] = mfma16(a1, kb1, Sacc[r]);
      }
    }
    __syncthreads();  // sync6
#pragma unroll
    for (int r = 0; r < 6; r++)
#pragma unroll
      for (int i = 0; i < 4; i++) {
        int dv = r * 16 + qd * 4 + i;
        STb[dv][w * 16 + l15] = __float2bfloat16(Sacc[r][i]);
      }
  }
}

// ---------------- fused gated RMSNorm -> bf16 (o and gate are bf16) ----------------
__global__ void gatednorm_bf_k(const bf16* __restrict__ o, const bf16* __restrict__ gate,
                               const float* __restrict__ onw, bf16* __restrict__ attn) {
  int wid = (blockIdx.x * blockDim.x + threadIdx.x) >> 6;
  int lane = threadIdx.x & 63;
  const bf16* orow = o + (size_t)wid * DVn;
  const bf16* grow = gate + (size_t)wid * DVn;
  bf16* arow = attn + (size_t)wid * DVn;
  float v0 = __bfloat162float(orow[lane]);
  float v1 = (lane < 32) ? __bfloat162float(orow[64 + lane]) : 0.f;
  float ss = v0 * v0 + v1 * v1;
  for (int m = 32; m >= 1; m >>= 1) ss += __shfl_xor(ss, m, 64);
  float rs = rsqrtf(ss * (1.f / DVn) + 1e-5f);
  float g0 = __bfloat162float(grow[lane]);
  arow[lane] = __float2bfloat16(v0 * rs * onw[lane] * siluf(g0));
  if (lane < 32) {
    float g1 = __bfloat162float(grow[64 + lane]);
    arow[64 + lane] = __float2bfloat16(v1 * rs * onw[64 + lane] * siluf(g1));
  }
}

extern "C" void kernel_launch(void* const* d_in, const int* in_sizes, int n_in,
                              void* d_out, int out_size, void* d_ws, size_t ws_size,
                              hipStream_t stream) {
  const float* x       = (const float*)d_in[0];
  const float* norm1_w = (const float*)d_in[1];
  const float* q_w     = (const float*)d_in[2];
  const float* k_w     = (const float*)d_in[3];
  const float* v_w     = (const float*)d_in[4];
  const float* cq_w    = (const float*)d_in[5];
  const float* ck_w    = (const float*)d_in[6];
  const float* cv_w    = (const float*)d_in[7];
  const float* b_w     = (const float*)d_in[8];
  const float* a_w     = (const float*)d_in[9];
  const float* A_log   = (const float*)d_in[10];
  const float* dt_bias = (const float*)d_in[11];
  const float* g_w     = (const float*)d_in[12];
  const float* o_norm_w= (const float*)d_in[13];
  const float* o_w     = (const float*)d_in[14];
  const float* norm2_w = (const float*)d_in[15];
  const float* gate_w  = (const float*)d_in[16];
  const float* up_w    = (const float*)d_in[17];
  const float* down_w  = (const float*)d_in[18];
  char* wsb = (char*)d_ws;
  float* out = (float*)d_out;

  bf16*  hbf   = (bf16*)(wsb + WO_HBF);
  bf16*  qkvr  = (bf16*)(wsb + WO_QKVR);   // raw projections
  bf16*  qkvc  = (bf16*)(wsb + WO_QKVC);   // conv'd
  bf16*  oscb  = (bf16*)(wsb + WO_OSC);
  bf16*  attn  = (bf16*)(wsb + WO_ATTN);
  bf16*  actb  = (bf16*)(wsb + WO_ACT);
  bf16*  gateb = (bf16*)(wsb + WO_GATE);
  float* x1    = (float*)(wsb + WO_X1);
  float* ba    = (float*)(wsb + WO_BA);
  float* Gc    = (float*)(wsb + WO_GC);
  bf16*  Tg    = (bf16*)(wsb + WO_T);
  bf16*  Uvg   = (bf16*)(wsb + WO_UV);
  bf16*  wb    = (bf16*)(wsb + WO_WB);

  dim3 tb(32, 8);
  // 0. transpose-cast weights to bf16 [N][K]
  tcast_k<<<dim3(24, 32), tb, 0, stream>>>(q_w,    wb + WB_QKVT,              1024, 768);
  tcast_k<<<dim3(24, 32), tb, 0, stream>>>(k_w,    wb + WB_QKVT + 768 * 1024, 1024, 768);
  tcast_k<<<dim3(48, 32), tb, 0, stream>>>(v_w,    wb + WB_QKVT + 1536 * 1024,1024, 1536);
  tcast_k<<<dim3(48, 32), tb, 0, stream>>>(g_w,    wb + WB_GT,                1024, 1536);
  tcast_k<<<dim3(32, 48), tb, 0, stream>>>(o_w,    wb + WB_OT,                1536, 1024);
  tcast_k<<<dim3(96, 32), tb, 0, stream>>>(gate_w, wb + WB_GATET,             1024, 3072);
  tcast_k<<<dim3(96, 32), tb, 0, stream>>>(up_w,   wb + WB_UPT,               1024, 3072);
  tcast_k<<<dim3(32, 96), tb, 0, stream>>>(down_w, wb + WB_DOWNT,             3072, 1024);
  tcast_k<<<dim3(1, 32),  tb, 0, stream>>>(b_w,    wb + WB_ABT,               1024, 16);
  tcast_k<<<dim3(1, 32),  tb, 0, stream>>>(a_w,    wb + WB_ABT + 16 * 1024,   1024, 16);

  // 1. h_bf = rmsnorm(x)
  rmsnorm_bf_k<<<BT, 256, 0, stream>>>(x, norm1_w, hbf);
  // 2. raw qkv (bf16), ba (fp32), gate (bf16)
  gemm_mfma<<<dim3(24, 64), 256, 0, stream>>>(hbf, wb + WB_QKVT, qkvr, nullptr, 3072, 1024, 3072, 3);
  gemm_mfma<<<dim3(1, 64), 256, 0, stream>>>(hbf, wb + WB_ABT, ba, nullptr, 32, 1024, 32, 0);
  gemm_mfma<<<dim3(12, 64), 256, 0, stream>>>(hbf, wb + WB_GT, gateb, nullptr, 1536, 1024, 1536, 3);
  // 3. parallel conv+silu (qkvr -> qkvc), l2norm, beta/g
  convsilu2_k<<<dim3(QKVC / 256, BT / 8), 256, 0, stream>>>(qkvr, qkvc, cq_w, ck_w, cv_w);
  l2norm_k<<<(BT * 32) / 4, 256, 0, stream>>>(qkvc);
  betag_k<<<(BT * Hn) / 256, 256, 0, stream>>>(ba, A_log, dt_bias);
  // 4. chunked gated delta rule
  dn_p1<<<Bn * Hn * NC, 256, 0, stream>>>(qkvc, ba, Gc, Tg, Uvg);
  dn_p2<<<Bn * Hn, 256, 0, stream>>>(qkvc, ba, Gc, Tg, Uvg, oscb);
  // 5. gated RMSNorm -> attn (bf16)
  gatednorm_bf_k<<<(BT * Hn) / 4, 256, 0, stream>>>(oscb, gateb, o_norm_w, attn);
  // 6. x1 = x + attn @ o_w
  gemm_mfma<<<dim3(8, 64), 256, 0, stream>>>(attn, wb + WB_OT, x1, x, 1024, 1536, 1024, 0);
  // 7. h2 = rmsnorm(x1)
  rmsnorm_bf_k<<<BT, 256, 0, stream>>>(x1, norm2_w, hbf);
  // 8. act = silu(h2@gate_w) * (h2@up_w)
  gemm_mfma<<<dim3(24, 64), 256, 0, stream>>>(hbf, wb + WB_GATET, actb, nullptr, 3072, 1024, 3072, 1);
  gemm_mfma<<<dim3(24, 64), 256, 0, stream>>>(hbf, wb + WB_UPT, actb, nullptr, 3072, 1024, 3072, 2);
  // 9. out = x1 + act @ down_w
  gemm_mfma<<<dim3(8, 64), 256, 0, stream>>>(actb, wb + WB_DOWNT, out, x1, 1024, 3072, 1024, 0);
}

// Round 6
// 963.717 us; speedup vs baseline: 8.1016x; 1.0192x over previous
//
#include <hip/hip_runtime.h>
#include <hip/hip_bf16.h>
#include <math.h>

// Problem constants
constexpr int Bn = 4, Tn = 2048, Dn = 1024, Hn = 16, DKn = 48, DVn = 96, In = 3072;
constexpr int BT = Bn * Tn;               // 8192
constexpr int HDK = Hn * DKn;             // 768
constexpr int HDV = Hn * DVn;             // 1536
constexpr int QKVC = 2 * HDK + HDV;       // 3072
constexpr int CC = 64;                    // chunk length
constexpr int NC = Tn / CC;               // 32 chunks per (b,h)

using bf16 = __hip_bfloat16;
typedef __attribute__((ext_vector_type(8))) short bf16x8;
typedef __attribute__((ext_vector_type(4))) float f32x4;

// ---- Workspace layout (byte offsets) ----
constexpr size_t WO_HBF   = 0;              // h/h2 bf16 [8192][1024]     16 MB
constexpr size_t WO_QKVR  = 16777216;       // raw qkv 48MB; then A/B/St; then osc+attn; then act
constexpr size_t WO_OSC   = 16777216;       // osc bf16 [8192][1536]   (aliases A/B, dead by p2c)
constexpr size_t WO_ATTN  = 41943040;       // attn bf16 [8192][1536]  (written after p2c)
constexpr size_t WO_ACT   = 16777216;       // mlp act bf16 [8192][3072]
constexpr size_t WO_A     = 16777216;       // A bf16 [2048][48][48]  9.4 MB
constexpr size_t WO_B     = 26214400;       // B bf16 [2048][48][96]  18.9 MB
constexpr size_t WO_ST    = 45088768;       // St bf16 [2048][96][48] 18.9 MB (ends 63,963,136)
constexpr size_t WO_QKVC  = 67108864;       // conv'd qkv bf16 [8192][3072] 48 MB
constexpr size_t WO_GATE  = 117440512;      // gate bf16 [8192][1536]     24 MB
constexpr size_t WO_X1    = 142606336;      // x1 fp32 [8192][1024]       32 MB
constexpr size_t WO_BA    = 176160768;      // ba fp32 [8192][32]         1 MB
constexpr size_t WO_GC    = 177209344;      // Gc fp32 [64][2048]         0.5 MB
constexpr size_t WO_T     = 177733632;      // T bf16 [2048][64][64]      16.8 MB
constexpr size_t WO_UV    = 194510848;      // Uv bf16 [2048][64][96]     25.2 MB
constexpr size_t WO_WB    = 219676672;      // bf16 weights ~31.5 MB
// bf16-element offsets inside WB:
constexpr size_t WB_QKVT = 0;              // [3072][1024]
constexpr size_t WB_GT   = 3145728;        // [1536][1024]
constexpr size_t WB_OT   = 4718592;        // [1024][1536]
constexpr size_t WB_GATET= 6291456;        // [3072][1024]
constexpr size_t WB_UPT  = 9437184;        // [3072][1024]
constexpr size_t WB_DOWNT= 12582912;       // [1024][3072]
constexpr size_t WB_ABT  = 15728640;       // [32][1024]

__device__ __forceinline__ float sigmoidf_(float x) { return 1.f / (1.f + __expf(-x)); }
__device__ __forceinline__ float siluf(float x) { return x * sigmoidf_(x); }

__device__ __forceinline__ void glds16(const void* g, void* l) {
  __builtin_amdgcn_global_load_lds((const __attribute__((address_space(1))) void*)g,
                                   (__attribute__((address_space(3))) void*)l, 16, 0, 0);
}

__device__ __forceinline__ f32x4 mfma16(bf16x8 a, bf16x8 b, f32x4 c) {
  return __builtin_amdgcn_mfma_f32_16x16x32_bf16(a, b, c, 0, 0, 0);
}

__device__ __forceinline__ bf16x8 scale8(bf16x8 a, float s) {
  bf16x8 r;
#pragma unroll
  for (int e = 0; e < 8; e++) {
    float f = __bfloat162float(__ushort_as_bfloat16((unsigned short)a[e])) * s;
    r[e] = (short)__bfloat16_as_ushort(__float2bfloat16(f));
  }
  return r;
}

// ---------------- transpose-cast: in fp32 [R][C] -> out bf16 [C][R] ----------------
__global__ void tcast_k(const float* __restrict__ in, bf16* __restrict__ out, int R, int C) {
  __shared__ float t[32][33];
  int tx = threadIdx.x, ty = threadIdx.y;
  int c0 = blockIdx.x * 32, r0 = blockIdx.y * 32;
#pragma unroll
  for (int j = 0; j < 4; j++) {
    int r = ty + j * 8;
    float v = (c0 + tx < C) ? in[(size_t)(r0 + r) * C + c0 + tx] : 0.f;
    t[r][tx] = v;
  }
  __syncthreads();
#pragma unroll
  for (int j = 0; j < 4; j++) {
    int cc = ty + j * 8;
    if (c0 + cc < C) out[(size_t)(c0 + cc) * R + r0 + tx] = __float2bfloat16(t[tx][cc]);
  }
}

// ---------------- RMSNorm -> bf16 out ----------------
__global__ void rmsnorm_bf_k(const float* __restrict__ x, const float* __restrict__ w,
                             bf16* __restrict__ y) {
  int row = blockIdx.x;
  const float4* xr = (const float4*)(x + (size_t)row * Dn);
  int tid = threadIdx.x;
  float4 v = xr[tid];
  float ss = v.x * v.x + v.y * v.y + v.z * v.z + v.w * v.w;
  for (int m = 32; m >= 1; m >>= 1) ss += __shfl_xor(ss, m, 64);
  __shared__ float wsum[4];
  if ((tid & 63) == 0) wsum[tid >> 6] = ss;
  __syncthreads();
  ss = wsum[0] + wsum[1] + wsum[2] + wsum[3];
  float rs = rsqrtf(ss * (1.f / Dn) + 1e-5f);
  float4 wv = ((const float4*)w)[tid];
  bf16* yr = y + (size_t)row * Dn + tid * 4;
  yr[0] = __float2bfloat16(v.x * rs * wv.x);
  yr[1] = __float2bfloat16(v.y * rs * wv.y);
  yr[2] = __float2bfloat16(v.z * rs * wv.z);
  yr[3] = __float2bfloat16(v.w * rs * wv.w);
}

// ---------------- MFMA bf16 GEMM: C[8192,N] = A[8192,K] @ Bt[N,K]^T ----------------
// mode 0: fp32 out (+res). mode 1: bf16 silu(acc). mode 2: bf16 C_old*acc. mode 3: bf16 acc.
__global__ __launch_bounds__(256) void gemm_mfma(
    const bf16* __restrict__ A, const bf16* __restrict__ Bt,
    void* __restrict__ Cv, const float* __restrict__ res,
    int N, int K, int ldc, int mode) {
  __shared__ bf16 As[128 * 32];
  __shared__ bf16 Bs[128 * 32];
  int tid = threadIdx.x, lane = tid & 63, w = tid >> 6;
  int bm = blockIdx.y * 128, bn = blockIdx.x * 128;
  int wr = w >> 1, wc = w & 1;
  int srow = lane >> 2;
  int gq = (lane & 3) ^ ((lane >> 3) & 3);
  int qa = (lane >> 4) ^ ((lane >> 1) & 3);
  int arow_base = wr * 64 + (lane & 15);
  int brow_base = wc * 64 + (lane & 15);
  f32x4 acc[4][4];
#pragma unroll
  for (int m = 0; m < 4; m++)
#pragma unroll
    for (int n = 0; n < 4; n++) acc[m][n] = (f32x4){0.f, 0.f, 0.f, 0.f};

  for (int k0 = 0; k0 < K; k0 += 32) {
#pragma unroll
    for (int cc = 0; cc < 2; cc++) {
      int c = 2 * w + cc;
      int arow = bm + c * 16 + srow;
      glds16(A + (size_t)arow * K + k0 + gq * 8, &As[c * 512]);
      int brow = bn + c * 16 + srow; if (brow >= N) brow = 0;
      glds16(Bt + (size_t)brow * K + k0 + gq * 8, &Bs[c * 512]);
    }
    __syncthreads();
    bf16x8 af[4], bfr[4];
#pragma unroll
    for (int m = 0; m < 4; m++) {
      int r = arow_base + m * 16;
      af[m] = *(const bf16x8*)&As[r * 32 + qa * 8];
    }
#pragma unroll
    for (int n = 0; n < 4; n++) {
      int r = brow_base + n * 16;
      bfr[n] = *(const bf16x8*)&Bs[r * 32 + qa * 8];
    }
#pragma unroll
    for (int m = 0; m < 4; m++)
#pragma unroll
      for (int n = 0; n < 4; n++)
        acc[m][n] = mfma16(af[m], bfr[n], acc[m][n]);
    __syncthreads();
  }
#pragma unroll
  for (int m = 0; m < 4; m++) {
#pragma unroll
    for (int n = 0; n < 4; n++) {
      int col = bn + wc * 64 + n * 16 + (lane & 15);
      if (col >= N) continue;
#pragma unroll
      for (int i = 0; i < 4; i++) {
        int row = bm + wr * 64 + m * 16 + (lane >> 4) * 4 + i;
        float v = acc[m][n][i];
        size_t idx = (size_t)row * ldc + col;
        if (mode == 0) {
          if (res) v += res[idx];
          ((float*)Cv)[idx] = v;
        } else if (mode == 1) {
          ((bf16*)Cv)[idx] = __float2bfloat16(siluf(v));
        } else if (mode == 2) {
          bf16* Cp = (bf16*)Cv;
          float old = __bfloat162float(Cp[idx]);
          Cp[idx] = __float2bfloat16(old * v);
        } else {
          ((bf16*)Cv)[idx] = __float2bfloat16(v);
        }
      }
    }
  }
}

// ---------------- Parallel causal conv (K=4) + silu ----------------
__global__ __launch_bounds__(256) void convsilu2_k(const bf16* __restrict__ in,
                                                   bf16* __restrict__ outp,
                                                   const float* __restrict__ wq,
                                                   const float* __restrict__ wk,
                                                   const float* __restrict__ wv) {
  int tx = threadIdx.x & 31;
  int ty = threadIdx.x >> 5;
  int c = (blockIdx.x * 32 + tx) * 8;
  int gt = blockIdx.y * 8 + ty;
  int b = gt >> 11, t = gt & (Tn - 1);
  const float* wsrc = (c < HDK) ? (wq + c * 4)
                     : (c < 2 * HDK) ? (wk + (c - HDK) * 4)
                                     : (wv + (c - 2 * HDK) * 4);
  float4 W[8];
#pragma unroll
  for (int j = 0; j < 8; j++) W[j] = ((const float4*)wsrc)[j];
  const bf16* base = in + (size_t)b * Tn * QKVC + c;
  bf16x8 r[4];
  bf16x8 zero = {0, 0, 0, 0, 0, 0, 0, 0};
#pragma unroll
  for (int j = 0; j < 4; j++) {
    int tt = t - 3 + j;
    r[j] = (tt >= 0) ? *(const bf16x8*)(base + (size_t)tt * QKVC) : zero;
  }
  bf16x8 o;
#pragma unroll
  for (int ch = 0; ch < 8; ch++) {
    float x0 = __bfloat162float(__ushort_as_bfloat16((unsigned short)r[0][ch]));
    float x1 = __bfloat162float(__ushort_as_bfloat16((unsigned short)r[1][ch]));
    float x2 = __bfloat162float(__ushort_as_bfloat16((unsigned short)r[2][ch]));
    float x3 = __bfloat162float(__ushort_as_bfloat16((unsigned short)r[3][ch]));
    float y = x0 * W[ch].x + x1 * W[ch].y + x2 * W[ch].z + x3 * W[ch].w;
    o[ch] = (short)__bfloat16_as_ushort(__float2bfloat16(siluf(y)));
  }
  *(bf16x8*)(outp + (size_t)gt * QKVC + c) = o;
}

// ---------------- l2norm over 48-element head rows of q,k (bf16 in place) ----------------
__global__ void l2norm_k(bf16* __restrict__ qkv) {
  int wid = (blockIdx.x * blockDim.x + threadIdx.x) >> 6;
  int lane = threadIdx.x & 63;
  int t = wid >> 5, hr = wid & 31;
  bf16* p = qkv + (size_t)t * QKVC + hr * DKn;
  float v = (lane < DKn) ? __bfloat162float(p[lane]) : 0.f;
  float ss = v * v;
  for (int m = 32; m >= 1; m >>= 1) ss += __shfl_xor(ss, m, 64);
  float rs = rsqrtf(ss + 1e-6f);
  if (lane < DKn) p[lane] = __float2bfloat16(v * rs);
}

// ---------------- beta/g transform ----------------
__global__ void betag_k(float* __restrict__ ba, const float* __restrict__ A_log,
                        const float* __restrict__ dt_bias) {
  int i = blockIdx.x * blockDim.x + threadIdx.x;
  int h = i & 15, r = i >> 4;
  float bv = ba[(size_t)r * 32 + h];
  float av = ba[(size_t)r * 32 + 16 + h];
  ba[(size_t)r * 32 + h] = sigmoidf_(bv);
  float xx = av + dt_bias[h];
  float sp = (xx > 20.f) ? xx : log1pf(__expf(xx));
  ba[(size_t)r * 32 + 16 + h] = -__expf(A_log[h]) * sp;
}

// ---------------- P1: per-chunk WY precompute (unchanged) ----------------
__global__ __launch_bounds__(256) void dn_p1(const bf16* __restrict__ qkv,
                                             const float* __restrict__ ba,
                                             float* __restrict__ Gc_g,
                                             bf16* __restrict__ T_g,
                                             bf16* __restrict__ Uv_g) {
  __shared__ bf16 Kl[64][72];
  __shared__ bf16 Vl[64][100];
  __shared__ float Nl[64][68];
  __shared__ float Gcl[64], Bl[64];
  int cid = blockIdx.x;
  int nc = cid & (NC - 1);
  int bh = cid >> 5;
  int h = bh & 15, b = bh >> 4;
  int t0 = nc * CC;
  int tid = threadIdx.x, lane = tid & 63, w = tid >> 6;
  {
    int t = tid >> 2, p = tid & 3;
    const bf16* row = qkv + ((size_t)(b * Tn + t0 + t)) * QKVC;
    int c0 = p * 12;
#pragma unroll
    for (int j = 0; j < 12; ++j) Kl[t][c0 + j] = row[HDK + h * DKn + c0 + j];
    int j0 = p * 24;
#pragma unroll
    for (int j = 0; j < 24; ++j) Vl[t][j0 + j] = row[2 * HDK + h * DVn + j0 + j];
  }
  for (int i = tid; i < 64 * 24; i += 256) {
    int t = i / 24, c = 48 + (i % 24);
    Kl[t][c] = __float2bfloat16(0.f);
  }
  if (tid < 64) {
    size_t row = (size_t)(b * Tn + t0 + tid);
    float g = ba[row * 32 + 16 + h];
    float be = ba[row * 32 + h];
    float acc = g;
#pragma unroll
    for (int d = 1; d < 64; d <<= 1) {
      float o = __shfl_up(acc, d);
      if (tid >= d) acc += o;
    }
    Gcl[tid] = acc; Bl[tid] = be;
    Gc_g[(size_t)bh * Tn + t0 + tid] = acc;
  }
  __syncthreads();
  f32x4 dacc[4];
#pragma unroll
  for (int n = 0; n < 4; n++) dacc[n] = (f32x4){0.f, 0.f, 0.f, 0.f};
  {
    int arow = w * 16 + (lane & 15);
    int qd = lane >> 4;
    bf16x8 a0 = *(const bf16x8*)&Kl[arow][qd * 8];
    bf16x8 a1 = *(const bf16x8*)&Kl[arow][32 + qd * 8];
#pragma unroll
    for (int n = 0; n < 4; n++) {
      int brow = n * 16 + (lane & 15);
      bf16x8 b0 = *(const bf16x8*)&Kl[brow][qd * 8];
      bf16x8 b1 = *(const bf16x8*)&Kl[brow][32 + qd * 8];
      dacc[n] = mfma16(a0, b0, dacc[n]);
      dacc[n] = mfma16(a1, b1, dacc[n]);
    }
  }
#pragma unroll
  for (int i = 0; i < 4; i++) {
    int t = w * 16 + (lane >> 4) * 4 + i;
    float bt = Bl[t], gt = Gcl[t];
#pragma unroll
    for (int n = 0; n < 4; n++) {
      int s = n * 16 + (lane & 15);
      Nl[t][s] = (s < t) ? bt * __expf(gt - Gcl[s]) * dacc[n][i] : 0.f;
    }
  }
  __syncthreads();
  int c = tid;
  if (c < 160) {
    float R[64];
    if (c < 64) {
#pragma unroll
      for (int t = 0; t < 64; ++t) R[t] = (t == c) ? 1.f : 0.f;
    } else {
      int j = c - 64;
#pragma unroll
      for (int t = 0; t < 64; ++t) R[t] = Bl[t] * __bfloat162float(Vl[t][j]);
    }
#pragma unroll
    for (int t = 1; t < 64; ++t) {
      float a0 = 0.f, a1 = 0.f, a2 = 0.f, a3 = 0.f;
#pragma unroll
      for (int s = 0; s + 3 < t; s += 4) {
        float4 n4 = *(const float4*)&Nl[t][s];
        a0 += n4.x * R[s]; a1 += n4.y * R[s + 1];
        a2 += n4.z * R[s + 2]; a3 += n4.w * R[s + 3];
      }
#pragma unroll
      for (int s = t & ~3; s < t; ++s) a0 += Nl[t][s] * R[s];
      R[t] -= ((a0 + a1) + (a2 + a3));
    }
    if (c < 64) {
#pragma unroll
      for (int t = 0; t < 64; ++t)
        T_g[(size_t)cid * 4096 + t * 64 + c] = __float2bfloat16(R[t]);
    } else {
      int j = c - 64;
#pragma unroll
      for (int t = 0; t < 64; ++t)
        Uv_g[(size_t)cid * 6144 + t * 96 + j] = __float2bfloat16(R[t]);
    }
  }
}

// ---------------- P2a: per-chunk affine coefficients A_c [48x48], B_c [48x96] ----------------
// A = lamC*I - K^T D_d T D_bl K ;  B = K^T D_d Uv
__global__ __launch_bounds__(256) void dn_p2a(const bf16* __restrict__ qkv,
                                              const float* __restrict__ ba,
                                              const float* __restrict__ Gc_g,
                                              const bf16* __restrict__ T_g,
                                              const bf16* __restrict__ Uv_g,
                                              bf16* __restrict__ A_g,
                                              bf16* __restrict__ B_g) {
  __shared__ bf16 Kl[64][72];     // K [t][dk]
  __shared__ bf16 KTl[48][72];    // K^T [dk][t]
  __shared__ bf16 KTbl[48][72];   // (D_bl K)^T [dk][t]
  __shared__ bf16 Tl[64][72];     // T [t][s]
  __shared__ bf16 M2T[48][72];    // (D_d T D_bl K)^T [dk'][t]
  __shared__ bf16 UvdT[96][72];   // (D_d Uv)^T [dv][t]
  __shared__ float Gcl[64], Bl[64];
  int cid = blockIdx.x;
  int nc = cid & (NC - 1);
  int bh = cid >> 5;
  int h = bh & 15, b = bh >> 4;
  int t0 = nc * CC;
  int tid = threadIdx.x, lane = tid & 63, w = tid >> 6;
  int l15 = lane & 15, qd = lane >> 4;
  // loads
  {
    int t = tid >> 2, p = tid & 3;
    const bf16* row = qkv + ((size_t)(b * Tn + t0 + t)) * QKVC;
    int c0 = p * 12;
#pragma unroll
    for (int j = 0; j < 12; ++j) Kl[t][c0 + j] = row[HDK + h * DKn + c0 + j];
  }
  if (tid < 64) {
    size_t row = (size_t)(b * Tn + t0 + tid);
    Gcl[tid] = Gc_g[(size_t)bh * Tn + t0 + tid];
    Bl[tid] = ba[row * 32 + h];
  }
  for (int i = tid; i < 4096; i += 256)
    (&Tl[0][0])[(i >> 6) * 72 + (i & 63)] = T_g[(size_t)cid * 4096 + i];
  unsigned short uvr[24];
#pragma unroll
  for (int r = 0; r < 24; r++)
    uvr[r] = __bfloat16_as_ushort(Uv_g[(size_t)cid * 6144 + tid + 256 * r]);
  __syncthreads();  // sync1
  float g63 = Gcl[63];
  // build K^T, (D_bl K)^T, (D_d Uv)^T
  for (int i = tid; i < 48 * 64; i += 256) {
    int dk = i >> 6, t = i & 63;
    bf16 kv = Kl[t][dk];
    KTl[dk][t] = kv;
    float bl = Bl[t] * __expf(Gcl[t]);
    KTbl[dk][t] = __float2bfloat16(__bfloat162float(kv) * bl);
  }
#pragma unroll
  for (int r = 0; r < 24; r++) {
    int i = tid + 256 * r;
    int t = i / 96, dv = i % 96;
    float dd = __expf(g63 - Gcl[t]);
    UvdT[dv][t] = __float2bfloat16(
        __bfloat162float(__ushort_as_bfloat16(uvr[r])) * dd);
  }
  __syncthreads();  // sync2
  // M1 = T @ (D_bl K): C[t][dk], wave w = m-tile
  f32x4 m1[3];
#pragma unroll
  for (int n = 0; n < 3; n++) m1[n] = (f32x4){0.f, 0.f, 0.f, 0.f};
  {
    int arow = w * 16 + l15;
    bf16x8 a0 = *(const bf16x8*)&Tl[arow][qd * 8];
    bf16x8 a1 = *(const bf16x8*)&Tl[arow][32 + qd * 8];
#pragma unroll
    for (int n = 0; n < 3; n++) {
      int brow = n * 16 + l15;
      bf16x8 b0 = *(const bf16x8*)&KTbl[brow][qd * 8];
      bf16x8 b1 = *(const bf16x8*)&KTbl[brow][32 + qd * 8];
      m1[n] = mfma16(a0, b0, m1[n]);
      m1[n] = mfma16(a1, b1, m1[n]);
    }
  }
#pragma unroll
  for (int i = 0; i < 4; i++) {
    int tt = w * 16 + qd * 4 + i;
    float dd = __expf(g63 - Gcl[tt]);
#pragma unroll
    for (int n = 0; n < 3; n++) {
      int dk = n * 16 + l15;
      M2T[dk][tt] = __float2bfloat16(m1[n][i] * dd);
    }
  }
  __syncthreads();  // sync3
  // 27 tiles: 0..8 A-part (3x3), 9..26 B-part (3x6); k over t=64
  float lamC = __expf(g63);
#pragma unroll
  for (int tswap = 0; tswap < 7; tswap++) {
    int t = w + 4 * tswap;
    if (t >= 27) break;
    int mi, ni; bool isA;
    if (t < 9) { isA = true; mi = t / 3; ni = t % 3; }
    else { isA = false; mi = (t - 9) / 6; ni = (t - 9) % 6; }
    f32x4 acc = (f32x4){0.f, 0.f, 0.f, 0.f};
    int arow = mi * 16 + l15;
    bf16x8 a0 = *(const bf16x8*)&KTl[arow][qd * 8];
    bf16x8 a1 = *(const bf16x8*)&KTl[arow][32 + qd * 8];
    int brow = ni * 16 + l15;
    if (isA) {
      bf16x8 b0 = *(const bf16x8*)&M2T[brow][qd * 8];
      bf16x8 b1 = *(const bf16x8*)&M2T[brow][32 + qd * 8];
      acc = mfma16(a0, b0, acc);
      acc = mfma16(a1, b1, acc);
#pragma unroll
      for (int i = 0; i < 4; i++) {
        int row = mi * 16 + qd * 4 + i, colv = ni * 16 + l15;
        float v = ((row == colv) ? lamC : 0.f) - acc[i];
        A_g[(size_t)cid * 2304 + row * 48 + colv] = __float2bfloat16(v);
      }
    } else {
      bf16x8 b0 = *(const bf16x8*)&UvdT[brow][qd * 8];
      bf16x8 b1 = *(const bf16x8*)&UvdT[brow][32 + qd * 8];
      acc = mfma16(a0, b0, acc);
      acc = mfma16(a1, b1, acc);
#pragma unroll
      for (int i = 0; i < 4; i++) {
        int row = mi * 16 + qd * 4 + i, colv = ni * 16 + l15;
        B_g[(size_t)cid * 4608 + row * 96 + colv] = __float2bfloat16(acc[i]);
      }
    }
  }
}

// ---------------- P2b: serial affine scan S' = A S + B; stores chunk-START S^T ----------------
__global__ __launch_bounds__(256) void dn_p2b(const bf16* __restrict__ A_g,
                                              const bf16* __restrict__ B_g,
                                              bf16* __restrict__ St_g) {
  __shared__ bf16 STl[96][72];   // S^T [dv][dk], cols 48..63 zero
  __shared__ bf16 Al[48][72];    // A [i][k],     cols 48..63 zero
  int bh = blockIdx.x;
  int tid = threadIdx.x, lane = tid & 63, w = tid >> 6;
  int l15 = lane & 15, qd = lane >> 4;
  bf16 zb = __float2bfloat16(0.f);
  for (int i = tid; i < 96 * 72; i += 256) (&STl[0][0])[i] = zb;
  for (int i = tid; i < 48 * 72; i += 256) (&Al[0][0])[i] = zb;
  __syncthreads();
  for (int c = 0; c < NC; ++c) {
    size_t cid = (size_t)bh * NC + c;
    // store chunk-start state
    for (int i = tid; i < 4608; i += 256)
      St_g[cid * 4608 + i] = STl[i / 48][i % 48];
    if (c == NC - 1) break;
    // load A_c
    for (int i = tid; i < 2304; i += 256)
      Al[i / 48][i % 48] = A_g[cid * 2304 + i];
    __syncthreads();
    // 18 tiles (m=6 dv-tiles, n=3 i-tiles); wave w takes t = w, w+4, ...
    float vals[5][4];
    int nt = 0;
#pragma unroll
    for (int ts = 0; ts < 5; ts++) {
      int t = w + 4 * ts;
      if (t >= 18) break;
      int mi = t / 3, ni = t % 3;
      f32x4 acc = (f32x4){0.f, 0.f, 0.f, 0.f};
      int arow = mi * 16 + l15;
      bf16x8 a0 = *(const bf16x8*)&STl[arow][qd * 8];
      bf16x8 a1 = *(const bf16x8*)&STl[arow][32 + qd * 8];
      int brow = ni * 16 + l15;
      bf16x8 b0 = *(const bf16x8*)&Al[brow][qd * 8];
      bf16x8 b1 = *(const bf16x8*)&Al[brow][32 + qd * 8];
      acc = mfma16(a0, b0, acc);
      acc = mfma16(a1, b1, acc);
#pragma unroll
      for (int i = 0; i < 4; i++) {
        int dv = mi * 16 + qd * 4 + i, ii = ni * 16 + l15;
        vals[ts][i] = acc[i] +
            __bfloat162float(B_g[cid * 4608 + ii * 96 + dv]);
      }
      nt = ts + 1;
    }
    __syncthreads();
#pragma unroll
    for (int ts = 0; ts < 5; ts++) {
      if (ts >= nt) break;
      int t = w + 4 * ts;
      int mi = t / 3, ni = t % 3;
#pragma unroll
      for (int i = 0; i < 4; i++) {
        int dv = mi * 16 + qd * 4 + i, ii = ni * 16 + l15;
        STl[dv][ii] = __float2bfloat16(vals[ts][i]);
      }
    }
    __syncthreads();
  }
}

// ---------------- P2c: per-chunk output (fully parallel) ----------------
__global__ __launch_bounds__(256) void dn_p2c(const bf16* __restrict__ qkv,
                                              const float* __restrict__ ba,
                                              const float* __restrict__ Gc_g,
                                              const bf16* __restrict__ T_g,
                                              const bf16* __restrict__ Uv_g,
                                              const bf16* __restrict__ St_g,
                                              bf16* __restrict__ osc) {
  __shared__ bf16 Kl[64][72], Ql[64][72], Tl[64][72], Ml[64][72];
  __shared__ bf16 G1T[96][72], UT[96][72], STb[96][72];
  __shared__ float Gcl[64], Bl[64];
  int cid = blockIdx.x;
  int nc = cid & (NC - 1);
  int bh = cid >> 5;
  int h = bh & 15, b = bh >> 4;
  int t0 = nc * CC;
  int tid = threadIdx.x, lane = tid & 63, w = tid >> 6;
  int l15 = lane & 15, qd = lane >> 4;
  const float scale = 0.14433756729740643f;  // 48^-0.5
  bf16 zb = __float2bfloat16(0.f);
  // loads
  {
    int t = tid >> 2, p = tid & 3;
    size_t grow = (size_t)(b * Tn + t0 + t);
    const bf16* row = qkv + grow * QKVC;
    int c0 = p * 12;
#pragma unroll
    for (int j = 0; j < 12; ++j) {
      int cc = c0 + j;
      Kl[t][cc] = row[HDK + h * DKn + cc];
      Ql[t][cc] = __float2bfloat16(__bfloat162float(row[h * DKn + cc]) * scale);
    }
    if (p == 0) { Gcl[t] = Gc_g[(size_t)bh * Tn + t0 + t]; Bl[t] = ba[grow * 32 + h]; }
  }
  for (int i = tid; i < 64 * 16; i += 256) {
    int t = i >> 4, cc = 48 + (i & 15);
    Kl[t][cc] = zb; Ql[t][cc] = zb;
  }
  for (int i = tid; i < 4096; i += 256)
    (&Tl[0][0])[(i >> 6) * 72 + (i & 63)] = T_g[(size_t)cid * 4096 + i];
  for (int i = tid; i < 4608; i += 256)
    STb[i / 48][i % 48] = St_g[(size_t)cid * 4608 + i];
  for (int i = tid; i < 96 * 16; i += 256)
    STb[i >> 4][48 + (i & 15)] = zb;
  __syncthreads();  // sync1
  // G1 = K @ S^T -> G1T scaled by beta*lambda
  f32x4 acc[6];
#pragma unroll
  for (int n = 0; n < 6; n++) acc[n] = (f32x4){0.f, 0.f, 0.f, 0.f};
  {
    int arow = w * 16 + l15;
    bf16x8 a0 = *(const bf16x8*)&Kl[arow][qd * 8];
    bf16x8 a1 = *(const bf16x8*)&Kl[arow][32 + qd * 8];
#pragma unroll
    for (int n = 0; n < 6; n++) {
      int brow = n * 16 + l15;
      bf16x8 b0 = *(const bf16x8*)&STb[brow][qd * 8];
      bf16x8 b1 = *(const bf16x8*)&STb[brow][32 + qd * 8];
      acc[n] = mfma16(a0, b0, acc[n]);
      acc[n] = mfma16(a1, b1, acc[n]);
    }
  }
#pragma unroll
  for (int i = 0; i < 4; i++) {
    int tt = w * 16 + qd * 4 + i;
    float sc = Bl[tt] * __expf(Gcl[tt]);
#pragma unroll
    for (int n = 0; n < 6; n++)
      G1T[n * 16 + l15][tt] = __float2bfloat16(acc[n][i] * sc);
  }
  __syncthreads();  // sync2
  // G2 = T@G1 ; U = Uv - G2 -> UT
#pragma unroll
  for (int n = 0; n < 6; n++) acc[n] = (f32x4){0.f, 0.f, 0.f, 0.f};
  {
    int arow = w * 16 + l15;
    bf16x8 a0 = *(const bf16x8*)&Tl[arow][qd * 8];
    bf16x8 a1 = *(const bf16x8*)&Tl[arow][32 + qd * 8];
#pragma unroll
    for (int n = 0; n < 6; n++) {
      int brow = n * 16 + l15;
      bf16x8 b0 = *(const bf16x8*)&G1T[brow][qd * 8];
      bf16x8 b1 = *(const bf16x8*)&G1T[brow][32 + qd * 8];
      acc[n] = mfma16(a0, b0, acc[n]);
      acc[n] = mfma16(a1, b1, acc[n]);
    }
  }
#pragma unroll
  for (int i = 0; i < 4; i++) {
    int tt = w * 16 + qd * 4 + i;
#pragma unroll
    for (int n = 0; n < 6; n++) {
      int dv = n * 16 + l15;
      float uv = __bfloat162float(Uv_g[(size_t)cid * 6144 + tt * 96 + dv]);
      UT[dv][tt] = __float2bfloat16(uv - acc[n][i]);
    }
  }
  // M = decay-masked QK^T (inclusive)
  f32x4 qk[4];
#pragma unroll
  for (int n = 0; n < 4; n++) qk[n] = (f32x4){0.f, 0.f, 0.f, 0.f};
  {
    int arow = w * 16 + l15;
    bf16x8 a0 = *(const bf16x8*)&Ql[arow][qd * 8];
    bf16x8 a1 = *(const bf16x8*)&Ql[arow][32 + qd * 8];
#pragma unroll
    for (int n = 0; n < 4; n++) {
      int brow = n * 16 + l15;
      bf16x8 b0 = *(const bf16x8*)&Kl[brow][qd * 8];
      bf16x8 b1 = *(const bf16x8*)&Kl[brow][32 + qd * 8];
      qk[n] = mfma16(a0, b0, qk[n]);
      qk[n] = mfma16(a1, b1, qk[n]);
    }
  }
#pragma unroll
  for (int i = 0; i < 4; i++) {
    int tt = w * 16 + qd * 4 + i;
    float gt = Gcl[tt];
#pragma unroll
    for (int n = 0; n < 4; n++) {
      int ss = n * 16 + l15;
      float m = (ss <= tt) ? qk[n][i] * __expf(gt - Gcl[ss]) : 0.f;
      Ml[tt][ss] = __float2bfloat16(m);
    }
  }
  __syncthreads();  // sync3
  // o = Qlam @ S^T + M @ U
#pragma unroll
  for (int n = 0; n < 6; n++) acc[n] = (f32x4){0.f, 0.f, 0.f, 0.f};
  {
    int arow = w * 16 + l15;
    float lam = __expf(Gcl[arow]);
    bf16x8 a0 = scale8(*(const bf16x8*)&Ql[arow][qd * 8], lam);
    bf16x8 a1 = scale8(*(const bf16x8*)&Ql[arow][32 + qd * 8], lam);
    bf16x8 m0 = *(const bf16x8*)&Ml[arow][qd * 8];
    bf16x8 m1 = *(const bf16x8*)&Ml[arow][32 + qd * 8];
#pragma unroll
    for (int n = 0; n < 6; n++) {
      int brow = n * 16 + l15;
      bf16x8 b0 = *(const bf16x8*)&STb[brow][qd * 8];
      bf16x8 b1 = *(const bf16x8*)&STb[brow][32 + qd * 8];
      acc[n] = mfma16(a0, b0, acc[n]);
      acc[n] = mfma16(a1, b1, acc[n]);
      bf16x8 u0 = *(const bf16x8*)&UT[brow][qd * 8];
      bf16x8 u1 = *(const bf16x8*)&UT[brow][32 + qd * 8];
      acc[n] = mfma16(m0, u0, acc[n]);
      acc[n] = mfma16(m1, u1, acc[n]);
    }
  }
#pragma unroll
  for (int i = 0; i < 4; i++) {
    int tt = w * 16 + qd * 4 + i;
    size_t orow = ((size_t)(b * Tn + t0 + tt)) * HDV + h * DVn;
#pragma unroll
    for (int n = 0; n < 6; n++)
      osc[orow + n * 16 + l15] = __float2bfloat16(acc[n][i]);
  }
}

// ---------------- fused gated RMSNorm -> bf16 ----------------
__global__ void gatednorm_bf_k(const bf16* __restrict__ o, const bf16* __restrict__ gate,
                               const float* __restrict__ onw, bf16* __restrict__ attn) {
  int wid = (blockIdx.x * blockDim.x + threadIdx.x) >> 6;
  int lane = threadIdx.x & 63;
  const bf16* orow = o + (size_t)wid * DVn;
  const bf16* grow = gate + (size_t)wid * DVn;
  bf16* arow = attn + (size_t)wid * DVn;
  float v0 = __bfloat162float(orow[lane]);
  float v1 = (lane < 32) ? __bfloat162float(orow[64 + lane]) : 0.f;
  float ss = v0 * v0 + v1 * v1;
  for (int m = 32; m >= 1; m >>= 1) ss += __shfl_xor(ss, m, 64);
  float rs = rsqrtf(ss * (1.f / DVn) + 1e-5f);
  float g0 = __bfloat162float(grow[lane]);
  arow[lane] = __float2bfloat16(v0 * rs * onw[lane] * siluf(g0));
  if (lane < 32) {
    float g1 = __bfloat162float(grow[64 + lane]);
    arow[64 + lane] = __float2bfloat16(v1 * rs * onw[64 + lane] * siluf(g1));
  }
}

extern "C" void kernel_launch(void* const* d_in, const int* in_sizes, int n_in,
                              void* d_out, int out_size, void* d_ws, size_t ws_size,
                              hipStream_t stream) {
  const float* x       = (const float*)d_in[0];
  const float* norm1_w = (const float*)d_in[1];
  const float* q_w     = (const float*)d_in[2];
  const float* k_w     = (const float*)d_in[3];
  const float* v_w     = (const float*)d_in[4];
  const float* cq_w    = (const float*)d_in[5];
  const float* ck_w    = (const float*)d_in[6];
  const float* cv_w    = (const float*)d_in[7];
  const float* b_w     = (const float*)d_in[8];
  const float* a_w     = (const float*)d_in[9];
  const float* A_log   = (const float*)d_in[10];
  const float* dt_bias = (const float*)d_in[11];
  const float* g_w     = (const float*)d_in[12];
  const float* o_norm_w= (const float*)d_in[13];
  const float* o_w     = (const float*)d_in[14];
  const float* norm2_w = (const float*)d_in[15];
  const float* gate_w  = (const float*)d_in[16];
  const float* up_w    = (const float*)d_in[17];
  const float* down_w  = (const float*)d_in[18];
  char* wsb = (char*)d_ws;
  float* out = (float*)d_out;

  bf16*  hbf   = (bf16*)(wsb + WO_HBF);
  bf16*  qkvr  = (bf16*)(wsb + WO_QKVR);
  bf16*  qkvc  = (bf16*)(wsb + WO_QKVC);
  bf16*  oscb  = (bf16*)(wsb + WO_OSC);
  bf16*  attn  = (bf16*)(wsb + WO_ATTN);
  bf16*  actb  = (bf16*)(wsb + WO_ACT);
  bf16*  gateb = (bf16*)(wsb + WO_GATE);
  float* x1    = (float*)(wsb + WO_X1);
  float* ba    = (float*)(wsb + WO_BA);
  float* Gc    = (float*)(wsb + WO_GC);
  bf16*  Tg    = (bf16*)(wsb + WO_T);
  bf16*  Uvg   = (bf16*)(wsb + WO_UV);
  bf16*  A_g   = (bf16*)(wsb + WO_A);
  bf16*  B_g   = (bf16*)(wsb + WO_B);
  bf16*  St_g  = (bf16*)(wsb + WO_ST);
  bf16*  wb    = (bf16*)(wsb + WO_WB);

  dim3 tb(32, 8);
  // 0. transpose-cast weights to bf16 [N][K]
  tcast_k<<<dim3(24, 32), tb, 0, stream>>>(q_w,    wb + WB_QKVT,              1024, 768);
  tcast_k<<<dim3(24, 32), tb, 0, stream>>>(k_w,    wb + WB_QKVT + 768 * 1024, 1024, 768);
  tcast_k<<<dim3(48, 32), tb, 0, stream>>>(v_w,    wb + WB_QKVT + 1536 * 1024,1024, 1536);
  tcast_k<<<dim3(48, 32), tb, 0, stream>>>(g_w,    wb + WB_GT,                1024, 1536);
  tcast_k<<<dim3(32, 48), tb, 0, stream>>>(o_w,    wb + WB_OT,                1536, 1024);
  tcast_k<<<dim3(96, 32), tb, 0, stream>>>(gate_w, wb + WB_GATET,             1024, 3072);
  tcast_k<<<dim3(96, 32), tb, 0, stream>>>(up_w,   wb + WB_UPT,               1024, 3072);
  tcast_k<<<dim3(32, 96), tb, 0, stream>>>(down_w, wb + WB_DOWNT,             3072, 1024);
  tcast_k<<<dim3(1, 32),  tb, 0, stream>>>(b_w,    wb + WB_ABT,               1024, 16);
  tcast_k<<<dim3(1, 32),  tb, 0, stream>>>(a_w,    wb + WB_ABT + 16 * 1024,   1024, 16);

  // 1. h_bf = rmsnorm(x)
  rmsnorm_bf_k<<<BT, 256, 0, stream>>>(x, norm1_w, hbf);
  // 2. projections
  gemm_mfma<<<dim3(24, 64), 256, 0, stream>>>(hbf, wb + WB_QKVT, qkvr, nullptr, 3072, 1024, 3072, 3);
  gemm_mfma<<<dim3(1, 64), 256, 0, stream>>>(hbf, wb + WB_ABT, ba, nullptr, 32, 1024, 32, 0);
  gemm_mfma<<<dim3(12, 64), 256, 0, stream>>>(hbf, wb + WB_GT, gateb, nullptr, 1536, 1024, 1536, 3);
  // 3. conv+silu, l2norm, beta/g
  convsilu2_k<<<dim3(QKVC / 256, BT / 8), 256, 0, stream>>>(qkvr, qkvc, cq_w, ck_w, cv_w);
  l2norm_k<<<(BT * 32) / 4, 256, 0, stream>>>(qkvc);
  betag_k<<<(BT * Hn) / 256, 256, 0, stream>>>(ba, A_log, dt_bias);
  // 4. chunked gated delta rule: WY precompute -> affine coeffs -> state scan -> outputs
  dn_p1<<<Bn * Hn * NC, 256, 0, stream>>>(qkvc, ba, Gc, Tg, Uvg);
  dn_p2a<<<Bn * Hn * NC, 256, 0, stream>>>(qkvc, ba, Gc, Tg, Uvg, A_g, B_g);
  dn_p2b<<<Bn * Hn, 256, 0, stream>>>(A_g, B_g, St_g);
  dn_p2c<<<Bn * Hn * NC, 256, 0, stream>>>(qkvc, ba, Gc, Tg, Uvg, St_g, oscb);
  // 5. gated RMSNorm -> attn (bf16)
  gatednorm_bf_k<<<(BT * Hn) / 4, 256, 0, stream>>>(oscb, gateb, o_norm_w, attn);
  // 6. x1 = x + attn @ o_w
  gemm_mfma<<<dim3(8, 64), 256, 0, stream>>>(attn, wb + WB_OT, x1, x, 1024, 1536, 1024, 0);
  // 7. h2 = rmsnorm(x1)
  rmsnorm_bf_k<<<BT, 256, 0, stream>>>(x1, norm2_w, hbf);
  // 8. act = silu(h2@gate_w) * (h2@up_w)
  gemm_mfma<<<dim3(24, 64), 256, 0, stream>>>(hbf, wb + WB_GATET, actb, nullptr, 3072, 1024, 3072, 1);
  gemm_mfma<<<dim3(24, 64), 256, 0, stream>>>(hbf, wb + WB_UPT, actb, nullptr, 3072, 1024, 3072, 2);
  // 9. out = x1 + act @ down_w
  gemm_mfma<<<dim3(8, 64), 256, 0, stream>>>(actb, wb + WB_DOWNT, out, x1, 1024, 3072, 1024, 0);
}

// Round 7
// 861.416 us; speedup vs baseline: 9.0638x; 1.1188x over previous
//
#include <hip/hip_runtime.h>
#include <hip/hip_bf16.h>
#include <math.h>

// Problem constants
constexpr int Bn = 4, Tn = 2048, Dn = 1024, Hn = 16, DKn = 48, DVn = 96, In = 3072;
constexpr int BT = Bn * Tn;               // 8192
constexpr int HDK = Hn * DKn;             // 768
constexpr int HDV = Hn * DVn;             // 1536
constexpr int QKVC = 2 * HDK + HDV;       // 3072
constexpr int CC = 64;                    // chunk length
constexpr int NC = Tn / CC;               // 32 chunks per (b,h)

using bf16 = __hip_bfloat16;
typedef __attribute__((ext_vector_type(8))) short bf16x8;
typedef __attribute__((ext_vector_type(4))) float f32x4;

// ---- Workspace layout (byte offsets) ----
constexpr size_t WO_HBF   = 0;              // h/h2 bf16 [8192][1024]     16 MB
constexpr size_t WO_QKVR  = 16777216;       // raw qkv 48MB; then A/B/St; then osc+attn; then act
constexpr size_t WO_OSC   = 16777216;       // osc bf16 [8192][1536]   (aliases A/B, dead by p2c)
constexpr size_t WO_ATTN  = 41943040;       // attn bf16 [8192][1536]  (written after p2c)
constexpr size_t WO_ACT   = 16777216;       // mlp act bf16 [8192][3072]
constexpr size_t WO_A     = 16777216;       // A bf16 [2048][48][48]  9.4 MB
constexpr size_t WO_B     = 26214400;       // B bf16 [2048][48][96]  18.9 MB
constexpr size_t WO_ST    = 45088768;       // St bf16 [2048][96][48] 18.9 MB (ends 63,963,136)
constexpr size_t WO_QKVC  = 67108864;       // conv'd qkv bf16 [8192][3072] 48 MB
constexpr size_t WO_GATE  = 117440512;      // gate bf16 [8192][1536]     24 MB
constexpr size_t WO_X1    = 142606336;      // x1 fp32 [8192][1024]       32 MB
constexpr size_t WO_BA    = 176160768;      // ba fp32 [8192][32]         1 MB
constexpr size_t WO_GC    = 177209344;      // Gc fp32 [64][2048]         0.5 MB
constexpr size_t WO_T     = 177733632;      // T bf16 [2048][64][64]      16.8 MB
constexpr size_t WO_UV    = 194510848;      // Uv bf16 [2048][64][96]     25.2 MB
constexpr size_t WO_WB    = 219676672;      // bf16 weights ~31.5 MB
// bf16-element offsets inside WB:
constexpr size_t WB_QKVT = 0;              // [3072][1024]
constexpr size_t WB_GT   = 3145728;        // [1536][1024]
constexpr size_t WB_OT   = 4718592;        // [1024][1536]
constexpr size_t WB_GATET= 6291456;        // [3072][1024]
constexpr size_t WB_UPT  = 9437184;        // [3072][1024]
constexpr size_t WB_DOWNT= 12582912;       // [1024][3072]
constexpr size_t WB_ABT  = 15728640;       // [32][1024]

__device__ __forceinline__ float sigmoidf_(float x) { return 1.f / (1.f + __expf(-x)); }
__device__ __forceinline__ float siluf(float x) { return x * sigmoidf_(x); }

__device__ __forceinline__ void glds16(const void* g, void* l) {
  __builtin_amdgcn_global_load_lds((const __attribute__((address_space(1))) void*)g,
                                   (__attribute__((address_space(3))) void*)l, 16, 0, 0);
}

__device__ __forceinline__ f32x4 mfma16(bf16x8 a, bf16x8 b, f32x4 c) {
  return __builtin_amdgcn_mfma_f32_16x16x32_bf16(a, b, c, 0, 0, 0);
}

__device__ __forceinline__ bf16x8 scale8(bf16x8 a, float s) {
  bf16x8 r;
#pragma unroll
  for (int e = 0; e < 8; e++) {
    float f = __bfloat162float(__ushort_as_bfloat16((unsigned short)a[e])) * s;
    r[e] = (short)__bfloat16_as_ushort(__float2bfloat16(f));
  }
  return r;
}

// ---------------- transpose-cast: in fp32 [R][C] -> out bf16 [C][R] ----------------
__global__ void tcast_k(const float* __restrict__ in, bf16* __restrict__ out, int R, int C) {
  __shared__ float t[32][33];
  int tx = threadIdx.x, ty = threadIdx.y;
  int c0 = blockIdx.x * 32, r0 = blockIdx.y * 32;
#pragma unroll
  for (int j = 0; j < 4; j++) {
    int r = ty + j * 8;
    float v = (c0 + tx < C) ? in[(size_t)(r0 + r) * C + c0 + tx] : 0.f;
    t[r][tx] = v;
  }
  __syncthreads();
#pragma unroll
  for (int j = 0; j < 4; j++) {
    int cc = ty + j * 8;
    if (c0 + cc < C) out[(size_t)(c0 + cc) * R + r0 + tx] = __float2bfloat16(t[tx][cc]);
  }
}

// ---------------- RMSNorm -> bf16 out ----------------
__global__ void rmsnorm_bf_k(const float* __restrict__ x, const float* __restrict__ w,
                             bf16* __restrict__ y) {
  int row = blockIdx.x;
  const float4* xr = (const float4*)(x + (size_t)row * Dn);
  int tid = threadIdx.x;
  float4 v = xr[tid];
  float ss = v.x * v.x + v.y * v.y + v.z * v.z + v.w * v.w;
  for (int m = 32; m >= 1; m >>= 1) ss += __shfl_xor(ss, m, 64);
  __shared__ float wsum[4];
  if ((tid & 63) == 0) wsum[tid >> 6] = ss;
  __syncthreads();
  ss = wsum[0] + wsum[1] + wsum[2] + wsum[3];
  float rs = rsqrtf(ss * (1.f / Dn) + 1e-5f);
  float4 wv = ((const float4*)w)[tid];
  bf16* yr = y + (size_t)row * Dn + tid * 4;
  yr[0] = __float2bfloat16(v.x * rs * wv.x);
  yr[1] = __float2bfloat16(v.y * rs * wv.y);
  yr[2] = __float2bfloat16(v.z * rs * wv.z);
  yr[3] = __float2bfloat16(v.w * rs * wv.w);
}

// ---------------- MFMA bf16 GEMM: C[8192,N] = A[8192,K] @ Bt[N,K]^T ----------------
// mode 0: fp32 out (+res). mode 1: bf16 silu(acc). mode 2: bf16 C_old*acc. mode 3: bf16 acc.
__global__ __launch_bounds__(256) void gemm_mfma(
    const bf16* __restrict__ A, const bf16* __restrict__ Bt,
    void* __restrict__ Cv, const float* __restrict__ res,
    int N, int K, int ldc, int mode) {
  __shared__ bf16 As[128 * 32];
  __shared__ bf16 Bs[128 * 32];
  int tid = threadIdx.x, lane = tid & 63, w = tid >> 6;
  int bm = blockIdx.y * 128, bn = blockIdx.x * 128;
  int wr = w >> 1, wc = w & 1;
  int srow = lane >> 2;
  int gq = (lane & 3) ^ ((lane >> 3) & 3);
  int qa = (lane >> 4) ^ ((lane >> 1) & 3);
  int arow_base = wr * 64 + (lane & 15);
  int brow_base = wc * 64 + (lane & 15);
  f32x4 acc[4][4];
#pragma unroll
  for (int m = 0; m < 4; m++)
#pragma unroll
    for (int n = 0; n < 4; n++) acc[m][n] = (f32x4){0.f, 0.f, 0.f, 0.f};

  for (int k0 = 0; k0 < K; k0 += 32) {
#pragma unroll
    for (int cc = 0; cc < 2; cc++) {
      int c = 2 * w + cc;
      int arow = bm + c * 16 + srow;
      glds16(A + (size_t)arow * K + k0 + gq * 8, &As[c * 512]);
      int brow = bn + c * 16 + srow; if (brow >= N) brow = 0;
      glds16(Bt + (size_t)brow * K + k0 + gq * 8, &Bs[c * 512]);
    }
    __syncthreads();
    bf16x8 af[4], bfr[4];
#pragma unroll
    for (int m = 0; m < 4; m++) {
      int r = arow_base + m * 16;
      af[m] = *(const bf16x8*)&As[r * 32 + qa * 8];
    }
#pragma unroll
    for (int n = 0; n < 4; n++) {
      int r = brow_base + n * 16;
      bfr[n] = *(const bf16x8*)&Bs[r * 32 + qa * 8];
    }
#pragma unroll
    for (int m = 0; m < 4; m++)
#pragma unroll
      for (int n = 0; n < 4; n++)
        acc[m][n] = mfma16(af[m], bfr[n], acc[m][n]);
    __syncthreads();
  }
#pragma unroll
  for (int m = 0; m < 4; m++) {
#pragma unroll
    for (int n = 0; n < 4; n++) {
      int col = bn + wc * 64 + n * 16 + (lane & 15);
      if (col >= N) continue;
#pragma unroll
      for (int i = 0; i < 4; i++) {
        int row = bm + wr * 64 + m * 16 + (lane >> 4) * 4 + i;
        float v = acc[m][n][i];
        size_t idx = (size_t)row * ldc + col;
        if (mode == 0) {
          if (res) v += res[idx];
          ((float*)Cv)[idx] = v;
        } else if (mode == 1) {
          ((bf16*)Cv)[idx] = __float2bfloat16(siluf(v));
        } else if (mode == 2) {
          bf16* Cp = (bf16*)Cv;
          float old = __bfloat162float(Cp[idx]);
          Cp[idx] = __float2bfloat16(old * v);
        } else {
          ((bf16*)Cv)[idx] = __float2bfloat16(v);
        }
      }
    }
  }
}

// ---------------- Parallel causal conv (K=4) + silu ----------------
__global__ __launch_bounds__(256) void convsilu2_k(const bf16* __restrict__ in,
                                                   bf16* __restrict__ outp,
                                                   const float* __restrict__ wq,
                                                   const float* __restrict__ wk,
                                                   const float* __restrict__ wv) {
  int tx = threadIdx.x & 31;
  int ty = threadIdx.x >> 5;
  int c = (blockIdx.x * 32 + tx) * 8;
  int gt = blockIdx.y * 8 + ty;
  int b = gt >> 11, t = gt & (Tn - 1);
  const float* wsrc = (c < HDK) ? (wq + c * 4)
                     : (c < 2 * HDK) ? (wk + (c - HDK) * 4)
                                     : (wv + (c - 2 * HDK) * 4);
  float4 W[8];
#pragma unroll
  for (int j = 0; j < 8; j++) W[j] = ((const float4*)wsrc)[j];
  const bf16* base = in + (size_t)b * Tn * QKVC + c;
  bf16x8 r[4];
  bf16x8 zero = {0, 0, 0, 0, 0, 0, 0, 0};
#pragma unroll
  for (int j = 0; j < 4; j++) {
    int tt = t - 3 + j;
    r[j] = (tt >= 0) ? *(const bf16x8*)(base + (size_t)tt * QKVC) : zero;
  }
  bf16x8 o;
#pragma unroll
  for (int ch = 0; ch < 8; ch++) {
    float x0 = __bfloat162float(__ushort_as_bfloat16((unsigned short)r[0][ch]));
    float x1 = __bfloat162float(__ushort_as_bfloat16((unsigned short)r[1][ch]));
    float x2 = __bfloat162float(__ushort_as_bfloat16((unsigned short)r[2][ch]));
    float x3 = __bfloat162float(__ushort_as_bfloat16((unsigned short)r[3][ch]));
    float y = x0 * W[ch].x + x1 * W[ch].y + x2 * W[ch].z + x3 * W[ch].w;
    o[ch] = (short)__bfloat16_as_ushort(__float2bfloat16(siluf(y)));
  }
  *(bf16x8*)(outp + (size_t)gt * QKVC + c) = o;
}

// ---------------- l2norm over 48-element head rows of q,k (bf16 in place) ----------------
__global__ void l2norm_k(bf16* __restrict__ qkv) {
  int wid = (blockIdx.x * blockDim.x + threadIdx.x) >> 6;
  int lane = threadIdx.x & 63;
  int t = wid >> 5, hr = wid & 31;
  bf16* p = qkv + (size_t)t * QKVC + hr * DKn;
  float v = (lane < DKn) ? __bfloat162float(p[lane]) : 0.f;
  float ss = v * v;
  for (int m = 32; m >= 1; m >>= 1) ss += __shfl_xor(ss, m, 64);
  float rs = rsqrtf(ss + 1e-6f);
  if (lane < DKn) p[lane] = __float2bfloat16(v * rs);
}

// ---------------- beta/g transform ----------------
__global__ void betag_k(float* __restrict__ ba, const float* __restrict__ A_log,
                        const float* __restrict__ dt_bias) {
  int i = blockIdx.x * blockDim.x + threadIdx.x;
  int h = i & 15, r = i >> 4;
  float bv = ba[(size_t)r * 32 + h];
  float av = ba[(size_t)r * 32 + 16 + h];
  ba[(size_t)r * 32 + h] = sigmoidf_(bv);
  float xx = av + dt_bias[h];
  float sp = (xx > 20.f) ? xx : log1pf(__expf(xx));
  ba[(size_t)r * 32 + 16 + h] = -__expf(A_log[h]) * sp;
}

// ---------------- P1: per-chunk WY precompute ----------------
__global__ __launch_bounds__(256) void dn_p1(const bf16* __restrict__ qkv,
                                             const float* __restrict__ ba,
                                             float* __restrict__ Gc_g,
                                             bf16* __restrict__ T_g,
                                             bf16* __restrict__ Uv_g) {
  __shared__ bf16 Kl[64][72];
  __shared__ bf16 Vl[64][100];
  __shared__ float Nl[64][68];
  __shared__ float Gcl[64], Bl[64];
  int cid = blockIdx.x;
  int nc = cid & (NC - 1);
  int bh = cid >> 5;
  int h = bh & 15, b = bh >> 4;
  int t0 = nc * CC;
  int tid = threadIdx.x, lane = tid & 63, w = tid >> 6;
  {
    int t = tid >> 2, p = tid & 3;
    const bf16* row = qkv + ((size_t)(b * Tn + t0 + t)) * QKVC;
    int c0 = p * 12;
#pragma unroll
    for (int j = 0; j < 12; ++j) Kl[t][c0 + j] = row[HDK + h * DKn + c0 + j];
    int j0 = p * 24;
#pragma unroll
    for (int j = 0; j < 24; ++j) Vl[t][j0 + j] = row[2 * HDK + h * DVn + j0 + j];
  }
  for (int i = tid; i < 64 * 24; i += 256) {
    int t = i / 24, c = 48 + (i % 24);
    Kl[t][c] = __float2bfloat16(0.f);
  }
  if (tid < 64) {
    size_t row = (size_t)(b * Tn + t0 + tid);
    float g = ba[row * 32 + 16 + h];
    float be = ba[row * 32 + h];
    float acc = g;
#pragma unroll
    for (int d = 1; d < 64; d <<= 1) {
      float o = __shfl_up(acc, d);
      if (tid >= d) acc += o;
    }
    Gcl[tid] = acc; Bl[tid] = be;
    Gc_g[(size_t)bh * Tn + t0 + tid] = acc;
  }
  __syncthreads();
  f32x4 dacc[4];
#pragma unroll
  for (int n = 0; n < 4; n++) dacc[n] = (f32x4){0.f, 0.f, 0.f, 0.f};
  {
    int arow = w * 16 + (lane & 15);
    int qd = lane >> 4;
    bf16x8 a0 = *(const bf16x8*)&Kl[arow][qd * 8];
    bf16x8 a1 = *(const bf16x8*)&Kl[arow][32 + qd * 8];
#pragma unroll
    for (int n = 0; n < 4; n++) {
      int brow = n * 16 + (lane & 15);
      bf16x8 b0 = *(const bf16x8*)&Kl[brow][qd * 8];
      bf16x8 b1 = *(const bf16x8*)&Kl[brow][32 + qd * 8];
      dacc[n] = mfma16(a0, b0, dacc[n]);
      dacc[n] = mfma16(a1, b1, dacc[n]);
    }
  }
#pragma unroll
  for (int i = 0; i < 4; i++) {
    int t = w * 16 + (lane >> 4) * 4 + i;
    float bt = Bl[t], gt = Gcl[t];
#pragma unroll
    for (int n = 0; n < 4; n++) {
      int s = n * 16 + (lane & 15);
      Nl[t][s] = (s < t) ? bt * __expf(gt - Gcl[s]) * dacc[n][i] : 0.f;
    }
  }
  __syncthreads();
  int c = tid;
  if (c < 160) {
    float R[64];
    if (c < 64) {
#pragma unroll
      for (int t = 0; t < 64; ++t) R[t] = (t == c) ? 1.f : 0.f;
    } else {
      int j = c - 64;
#pragma unroll
      for (int t = 0; t < 64; ++t) R[t] = Bl[t] * __bfloat162float(Vl[t][j]);
    }
#pragma unroll
    for (int t = 1; t < 64; ++t) {
      float a0 = 0.f, a1 = 0.f, a2 = 0.f, a3 = 0.f;
#pragma unroll
      for (int s = 0; s + 3 < t; s += 4) {
        float4 n4 = *(const float4*)&Nl[t][s];
        a0 += n4.x * R[s]; a1 += n4.y * R[s + 1];
        a2 += n4.z * R[s + 2]; a3 += n4.w * R[s + 3];
      }
#pragma unroll
      for (int s = t & ~3; s < t; ++s) a0 += Nl[t][s] * R[s];
      R[t] -= ((a0 + a1) + (a2 + a3));
    }
    if (c < 64) {
#pragma unroll
      for (int t = 0; t < 64; ++t)
        T_g[(size_t)cid * 4096 + t * 64 + c] = __float2bfloat16(R[t]);
    } else {
      int j = c - 64;
#pragma unroll
      for (int t = 0; t < 64; ++t)
        Uv_g[(size_t)cid * 6144 + t * 96 + j] = __float2bfloat16(R[t]);
    }
  }
}

// ---------------- P2a: per-chunk affine coefficients A_c [48x48], B_c [48x96] ----------------
__global__ __launch_bounds__(256) void dn_p2a(const bf16* __restrict__ qkv,
                                              const float* __restrict__ ba,
                                              const float* __restrict__ Gc_g,
                                              const bf16* __restrict__ T_g,
                                              const bf16* __restrict__ Uv_g,
                                              bf16* __restrict__ A_g,
                                              bf16* __restrict__ B_g) {
  __shared__ bf16 Kl[64][72];
  __shared__ bf16 KTl[48][72];
  __shared__ bf16 KTbl[48][72];
  __shared__ bf16 Tl[64][72];
  __shared__ bf16 M2T[48][72];
  __shared__ bf16 UvdT[96][72];
  __shared__ float Gcl[64], Bl[64];
  int cid = blockIdx.x;
  int nc = cid & (NC - 1);
  int bh = cid >> 5;
  int h = bh & 15, b = bh >> 4;
  int t0 = nc * CC;
  int tid = threadIdx.x, lane = tid & 63, w = tid >> 6;
  int l15 = lane & 15, qd = lane >> 4;
  {
    int t = tid >> 2, p = tid & 3;
    const bf16* row = qkv + ((size_t)(b * Tn + t0 + t)) * QKVC;
    int c0 = p * 12;
#pragma unroll
    for (int j = 0; j < 12; ++j) Kl[t][c0 + j] = row[HDK + h * DKn + c0 + j];
  }
  if (tid < 64) {
    size_t row = (size_t)(b * Tn + t0 + tid);
    Gcl[tid] = Gc_g[(size_t)bh * Tn + t0 + tid];
    Bl[tid] = ba[row * 32 + h];
  }
  for (int i = tid; i < 4096; i += 256)
    (&Tl[0][0])[(i >> 6) * 72 + (i & 63)] = T_g[(size_t)cid * 4096 + i];
  unsigned short uvr[24];
#pragma unroll
  for (int r = 0; r < 24; r++)
    uvr[r] = __bfloat16_as_ushort(Uv_g[(size_t)cid * 6144 + tid + 256 * r]);
  __syncthreads();  // sync1
  float g63 = Gcl[63];
  for (int i = tid; i < 48 * 64; i += 256) {
    int dk = i >> 6, t = i & 63;
    bf16 kv = Kl[t][dk];
    KTl[dk][t] = kv;
    float bl = Bl[t] * __expf(Gcl[t]);
    KTbl[dk][t] = __float2bfloat16(__bfloat162float(kv) * bl);
  }
#pragma unroll
  for (int r = 0; r < 24; r++) {
    int i = tid + 256 * r;
    int t = i / 96, dv = i % 96;
    float dd = __expf(g63 - Gcl[t]);
    UvdT[dv][t] = __float2bfloat16(
        __bfloat162float(__ushort_as_bfloat16(uvr[r])) * dd);
  }
  __syncthreads();  // sync2
  f32x4 m1[3];
#pragma unroll
  for (int n = 0; n < 3; n++) m1[n] = (f32x4){0.f, 0.f, 0.f, 0.f};
  {
    int arow = w * 16 + l15;
    bf16x8 a0 = *(const bf16x8*)&Tl[arow][qd * 8];
    bf16x8 a1 = *(const bf16x8*)&Tl[arow][32 + qd * 8];
#pragma unroll
    for (int n = 0; n < 3; n++) {
      int brow = n * 16 + l15;
      bf16x8 b0 = *(const bf16x8*)&KTbl[brow][qd * 8];
      bf16x8 b1 = *(const bf16x8*)&KTbl[brow][32 + qd * 8];
      m1[n] = mfma16(a0, b0, m1[n]);
      m1[n] = mfma16(a1, b1, m1[n]);
    }
  }
#pragma unroll
  for (int i = 0; i < 4; i++) {
    int tt = w * 16 + qd * 4 + i;
    float dd = __expf(g63 - Gcl[tt]);
#pragma unroll
    for (int n = 0; n < 3; n++) {
      int dk = n * 16 + l15;
      M2T[dk][tt] = __float2bfloat16(m1[n][i] * dd);
    }
  }
  __syncthreads();  // sync3
  float lamC = __expf(g63);
#pragma unroll
  for (int tswap = 0; tswap < 7; tswap++) {
    int t = w + 4 * tswap;
    if (t >= 27) break;
    int mi, ni; bool isA;
    if (t < 9) { isA = true; mi = t / 3; ni = t % 3; }
    else { isA = false; mi = (t - 9) / 6; ni = (t - 9) % 6; }
    f32x4 acc = (f32x4){0.f, 0.f, 0.f, 0.f};
    int arow = mi * 16 + l15;
    bf16x8 a0 = *(const bf16x8*)&KTl[arow][qd * 8];
    bf16x8 a1 = *(const bf16x8*)&KTl[arow][32 + qd * 8];
    int brow = ni * 16 + l15;
    if (isA) {
      bf16x8 b0 = *(const bf16x8*)&M2T[brow][qd * 8];
      bf16x8 b1 = *(const bf16x8*)&M2T[brow][32 + qd * 8];
      acc = mfma16(a0, b0, acc);
      acc = mfma16(a1, b1, acc);
#pragma unroll
      for (int i = 0; i < 4; i++) {
        int row = mi * 16 + qd * 4 + i, colv = ni * 16 + l15;
        float v = ((row == colv) ? lamC : 0.f) - acc[i];
        A_g[(size_t)cid * 2304 + row * 48 + colv] = __float2bfloat16(v);
      }
    } else {
      bf16x8 b0 = *(const bf16x8*)&UvdT[brow][qd * 8];
      bf16x8 b1 = *(const bf16x8*)&UvdT[brow][32 + qd * 8];
      acc = mfma16(a0, b0, acc);
      acc = mfma16(a1, b1, acc);
#pragma unroll
      for (int i = 0; i < 4; i++) {
        int row = mi * 16 + qd * 4 + i, colv = ni * 16 + l15;
        B_g[(size_t)cid * 4608 + row * 96 + colv] = __float2bfloat16(acc[i]);
      }
    }
  }
}

// ---------------- P2b: pipelined serial affine scan S' = A S + B ----------------
// Double-buffered LDS (STl/Al/Bl), 1 barrier/step, A/B reg-prefetched 1 iter ahead.
__global__ __launch_bounds__(256) void dn_p2b(const bf16* __restrict__ A_g,
                                              const bf16* __restrict__ B_g,
                                              bf16* __restrict__ St_g) {
  __shared__ bf16 STl[2][96][72];   // S^T [dv][dk], cols 48..71 zero
  __shared__ bf16 Al[2][48][72];    // A [i][k],     cols 48..71 zero
  __shared__ bf16 Bl[2][4608];      // B linear [i][dv]
  int bh = blockIdx.x;
  int tid = threadIdx.x, lane = tid & 63, w = tid >> 6;
  int l15 = lane & 15, qd = lane >> 4;
  bf16 zb = __float2bfloat16(0.f);
  // zero-init: whole STl (both buffers), Al pad cols 48..71 (both buffers)
  for (int i = tid; i < 2 * 96 * 72; i += 256) (&STl[0][0][0])[i] = zb;
  for (int i = tid; i < 2 * 48 * 24; i += 256) {
    int buf = i / (48 * 24), r = (i / 24) % 48, cc = 48 + (i % 24);
    Al[buf][r][cc] = zb;
  }
  // reg prefetch buffers
  bf16x8 ra0, ra1, rb0, rb1;
  unsigned int rb2;
  int e_a0 = tid * 8, e_a1 = 2048 + tid * 8;
  // prologue: load chunk-0 coeffs
  {
    size_t cid = (size_t)bh * NC;
    ra0 = *(const bf16x8*)(A_g + cid * 2304 + e_a0);
    if (tid < 32) ra1 = *(const bf16x8*)(A_g + cid * 2304 + e_a1);
    rb0 = *(const bf16x8*)(B_g + cid * 4608 + tid * 16);
    rb1 = *(const bf16x8*)(B_g + cid * 4608 + tid * 16 + 8);
    rb2 = *(const unsigned int*)(B_g + cid * 4608 + 4096 + tid * 2);
  }
  // stage into buffer 0
  *(bf16x8*)&Al[0][e_a0 / 48][e_a0 % 48] = ra0;
  if (tid < 32) *(bf16x8*)&Al[0][e_a1 / 48][e_a1 % 48] = ra1;
  *(bf16x8*)&Bl[0][tid * 16] = rb0;
  *(bf16x8*)&Bl[0][tid * 16 + 8] = rb1;
  *(unsigned int*)&Bl[0][4096 + tid * 2] = rb2;
  // issue chunk-1 loads
  {
    size_t cid = (size_t)bh * NC + 1;
    ra0 = *(const bf16x8*)(A_g + cid * 2304 + e_a0);
    if (tid < 32) ra1 = *(const bf16x8*)(A_g + cid * 2304 + e_a1);
    rb0 = *(const bf16x8*)(B_g + cid * 4608 + tid * 16);
    rb1 = *(const bf16x8*)(B_g + cid * 4608 + tid * 16 + 8);
    rb2 = *(const unsigned int*)(B_g + cid * 4608 + 4096 + tid * 2);
  }
  __syncthreads();

  for (int c = 0; c < NC - 1; ++c) {
    int cur = c & 1, nxt = cur ^ 1;
    size_t cid = (size_t)bh * NC + c;
    // store chunk-start state S_c^T (vectorized, fire-and-forget)
    {
      int e0 = tid * 8, e1 = 2048 + tid * 8, e2 = 4096 + tid * 2;
      *(bf16x8*)(St_g + cid * 4608 + e0) = *(const bf16x8*)&STl[cur][e0 / 48][e0 % 48];
      *(bf16x8*)(St_g + cid * 4608 + e1) = *(const bf16x8*)&STl[cur][e1 / 48][e1 % 48];
      *(unsigned int*)(St_g + cid * 4608 + e2) = *(const unsigned int*)&STl[cur][e2 / 48][e2 % 48];
    }
    // MFMA: vals = S^T·A^T + B   (18 tiles over 4 waves)
    float vals[5][4];
#pragma unroll
    for (int ts = 0; ts < 5; ts++) {
      int t = w + 4 * ts;
      if (t >= 18) break;
      int mi = t / 3, ni = t % 3;
      f32x4 acc = (f32x4){0.f, 0.f, 0.f, 0.f};
      int arow = mi * 16 + l15;
      bf16x8 a0 = *(const bf16x8*)&STl[cur][arow][qd * 8];
      bf16x8 a1 = *(const bf16x8*)&STl[cur][arow][32 + qd * 8];
      int brow = ni * 16 + l15;
      bf16x8 b0 = *(const bf16x8*)&Al[cur][brow][qd * 8];
      bf16x8 b1 = *(const bf16x8*)&Al[cur][brow][32 + qd * 8];
      acc = mfma16(a0, b0, acc);
      acc = mfma16(a1, b1, acc);
#pragma unroll
      for (int i = 0; i < 4; i++) {
        int dv = mi * 16 + qd * 4 + i, ii = ni * 16 + l15;
        vals[ts][i] = acc[i] + __bfloat162float(Bl[cur][ii * 96 + dv]);
      }
    }
    // write new state into STl[nxt]
#pragma unroll
    for (int ts = 0; ts < 5; ts++) {
      int t = w + 4 * ts;
      if (t >= 18) break;
      int mi = t / 3, ni = t % 3;
#pragma unroll
      for (int i = 0; i < 4; i++) {
        int dv = mi * 16 + qd * 4 + i, ii = ni * 16 + l15;
        STl[nxt][dv][ii] = __float2bfloat16(vals[ts][i]);
      }
    }
    // stage prefetched chunk c+1 coeffs into nxt buffers; issue chunk c+2 loads
    if (c + 1 <= NC - 2) {
      *(bf16x8*)&Al[nxt][e_a0 / 48][e_a0 % 48] = ra0;
      if (tid < 32) *(bf16x8*)&Al[nxt][e_a1 / 48][e_a1 % 48] = ra1;
      *(bf16x8*)&Bl[nxt][tid * 16] = rb0;
      *(bf16x8*)&Bl[nxt][tid * 16 + 8] = rb1;
      *(unsigned int*)&Bl[nxt][4096 + tid * 2] = rb2;
      if (c + 2 <= NC - 2) {
        size_t cid2 = (size_t)bh * NC + c + 2;
        ra0 = *(const bf16x8*)(A_g + cid2 * 2304 + e_a0);
        if (tid < 32) ra1 = *(const bf16x8*)(A_g + cid2 * 2304 + e_a1);
        rb0 = *(const bf16x8*)(B_g + cid2 * 4608 + tid * 16);
        rb1 = *(const bf16x8*)(B_g + cid2 * 4608 + tid * 16 + 8);
        rb2 = *(const unsigned int*)(B_g + cid2 * 4608 + 4096 + tid * 2);
      }
    }
    __syncthreads();
  }
  // final chunk-start state
  {
    size_t cid = (size_t)bh * NC + (NC - 1);
    int cur = (NC - 1) & 1;
    int e0 = tid * 8, e1 = 2048 + tid * 8, e2 = 4096 + tid * 2;
    *(bf16x8*)(St_g + cid * 4608 + e0) = *(const bf16x8*)&STl[cur][e0 / 48][e0 % 48];
    *(bf16x8*)(St_g + cid * 4608 + e1) = *(const bf16x8*)&STl[cur][e1 / 48][e1 % 48];
    *(unsigned int*)(St_g + cid * 4608 + e2) = *(const unsigned int*)&STl[cur][e2 / 48][e2 % 48];
  }
}

// ---------------- P2c: per-chunk output (fully parallel) ----------------
__global__ __launch_bounds__(256) void dn_p2c(const bf16* __restrict__ qkv,
                                              const float* __restrict__ ba,
                                              const float* __restrict__ Gc_g,
                                              const bf16* __restrict__ T_g,
                                              const bf16* __restrict__ Uv_g,
                                              const bf16* __restrict__ St_g,
                                              bf16* __restrict__ osc) {
  __shared__ bf16 Kl[64][72], Ql[64][72], Tl[64][72], Ml[64][72];
  __shared__ bf16 G1T[96][72], UT[96][72], STb[96][72];
  __shared__ float Gcl[64], Bl[64];
  int cid = blockIdx.x;
  int nc = cid & (NC - 1);
  int bh = cid >> 5;
  int h = bh & 15, b = bh >> 4;
  int t0 = nc * CC;
  int tid = threadIdx.x, lane = tid & 63, w = tid >> 6;
  int l15 = lane & 15, qd = lane >> 4;
  const float scale = 0.14433756729740643f;  // 48^-0.5
  bf16 zb = __float2bfloat16(0.f);
  {
    int t = tid >> 2, p = tid & 3;
    size_t grow = (size_t)(b * Tn + t0 + t);
    const bf16* row = qkv + grow * QKVC;
    int c0 = p * 12;
#pragma unroll
    for (int j = 0; j < 12; ++j) {
      int cc = c0 + j;
      Kl[t][cc] = row[HDK + h * DKn + cc];
      Ql[t][cc] = __float2bfloat16(__bfloat162float(row[h * DKn + cc]) * scale);
    }
    if (p == 0) { Gcl[t] = Gc_g[(size_t)bh * Tn + t0 + t]; Bl[t] = ba[grow * 32 + h]; }
  }
  for (int i = tid; i < 64 * 16; i += 256) {
    int t = i >> 4, cc = 48 + (i & 15);
    Kl[t][cc] = zb; Ql[t][cc] = zb;
  }
  for (int i = tid; i < 4096; i += 256)
    (&Tl[0][0])[(i >> 6) * 72 + (i & 63)] = T_g[(size_t)cid * 4096 + i];
  for (int i = tid; i < 4608; i += 256)
    STb[i / 48][i % 48] = St_g[(size_t)cid * 4608 + i];
  for (int i = tid; i < 96 * 16; i += 256)
    STb[i >> 4][48 + (i & 15)] = zb;
  __syncthreads();  // sync1
  f32x4 acc[6];
#pragma unroll
  for (int n = 0; n < 6; n++) acc[n] = (f32x4){0.f, 0.f, 0.f, 0.f};
  {
    int arow = w * 16 + l15;
    bf16x8 a0 = *(const bf16x8*)&Kl[arow][qd * 8];
    bf16x8 a1 = *(const bf16x8*)&Kl[arow][32 + qd * 8];
#pragma unroll
    for (int n = 0; n < 6; n++) {
      int brow = n * 16 + l15;
      bf16x8 b0 = *(const bf16x8*)&STb[brow][qd * 8];
      bf16x8 b1 = *(const bf16x8*)&STb[brow][32 + qd * 8];
      acc[n] = mfma16(a0, b0, acc[n]);
      acc[n] = mfma16(a1, b1, acc[n]);
    }
  }
#pragma unroll
  for (int i = 0; i < 4; i++) {
    int tt = w * 16 + qd * 4 + i;
    float sc = Bl[tt] * __expf(Gcl[tt]);
#pragma unroll
    for (int n = 0; n < 6; n++)
      G1T[n * 16 + l15][tt] = __float2bfloat16(acc[n][i] * sc);
  }
  __syncthreads();  // sync2
#pragma unroll
  for (int n = 0; n < 6; n++) acc[n] = (f32x4){0.f, 0.f, 0.f, 0.f};
  {
    int arow = w * 16 + l15;
    bf16x8 a0 = *(const bf16x8*)&Tl[arow][qd * 8];
    bf16x8 a1 = *(const bf16x8*)&Tl[arow][32 + qd * 8];
#pragma unroll
    for (int n = 0; n < 6; n++) {
      int brow = n * 16 + l15;
      bf16x8 b0 = *(const bf16x8*)&G1T[brow][qd * 8];
      bf16x8 b1 = *(const bf16x8*)&G1T[brow][32 + qd * 8];
      acc[n] = mfma16(a0, b0, acc[n]);
      acc[n] = mfma16(a1, b1, acc[n]);
    }
  }
#pragma unroll
  for (int i = 0; i < 4; i++) {
    int tt = w * 16 + qd * 4 + i;
#pragma unroll
    for (int n = 0; n < 6; n++) {
      int dv = n * 16 + l15;
      float uv = __bfloat162float(Uv_g[(size_t)cid * 6144 + tt * 96 + dv]);
      UT[dv][tt] = __float2bfloat16(uv - acc[n][i]);
    }
  }
  f32x4 qk[4];
#pragma unroll
  for (int n = 0; n < 4; n++) qk[n] = (f32x4){0.f, 0.f, 0.f, 0.f};
  {
    int arow = w * 16 + l15;
    bf16x8 a0 = *(const bf16x8*)&Ql[arow][qd * 8];
    bf16x8 a1 = *(const bf16x8*)&Ql[arow][32 + qd * 8];
#pragma unroll
    for (int n = 0; n < 4; n++) {
      int brow = n * 16 + l15;
      bf16x8 b0 = *(const bf16x8*)&Kl[brow][qd * 8];
      bf16x8 b1 = *(const bf16x8*)&Kl[brow][32 + qd * 8];
      qk[n] = mfma16(a0, b0, qk[n]);
      qk[n] = mfma16(a1, b1, qk[n]);
    }
  }
#pragma unroll
  for (int i = 0; i < 4; i++) {
    int tt = w * 16 + qd * 4 + i;
    float gt = Gcl[tt];
#pragma unroll
    for (int n = 0; n < 4; n++) {
      int ss = n * 16 + l15;
      float m = (ss <= tt) ? qk[n][i] * __expf(gt - Gcl[ss]) : 0.f;
      Ml[tt][ss] = __float2bfloat16(m);
    }
  }
  __syncthreads();  // sync3
#pragma unroll
  for (int n = 0; n < 6; n++) acc[n] = (f32x4){0.f, 0.f, 0.f, 0.f};
  {
    int arow = w * 16 + l15;
    float lam = __expf(Gcl[arow]);
    bf16x8 a0 = scale8(*(const bf16x8*)&Ql[arow][qd * 8], lam);
    bf16x8 a1 = scale8(*(const bf16x8*)&Ql[arow][32 + qd * 8], lam);
    bf16x8 m0 = *(const bf16x8*)&Ml[arow][qd * 8];
    bf16x8 m1 = *(const bf16x8*)&Ml[arow][32 + qd * 8];
#pragma unroll
    for (int n = 0; n < 6; n++) {
      int brow = n * 16 + l15;
      bf16x8 b0 = *(const bf16x8*)&STb[brow][qd * 8];
      bf16x8 b1 = *(const bf16x8*)&STb[brow][32 + qd * 8];
      acc[n] = mfma16(a0, b0, acc[n]);
      acc[n] = mfma16(a1, b1, acc[n]);
      bf16x8 u0 = *(const bf16x8*)&UT[brow][qd * 8];
      bf16x8 u1 = *(const bf16x8*)&UT[brow][32 + qd * 8];
      acc[n] = mfma16(m0, u0, acc[n]);
      acc[n] = mfma16(m1, u1, acc[n]);
    }
  }
#pragma unroll
  for (int i = 0; i < 4; i++) {
    int tt = w * 16 + qd * 4 + i;
    size_t orow = ((size_t)(b * Tn + t0 + tt)) * HDV + h * DVn;
#pragma unroll
    for (int n = 0; n < 6; n++)
      osc[orow + n * 16 + l15] = __float2bfloat16(acc[n][i]);
  }
}

// ---------------- fused gated RMSNorm -> bf16 ----------------
__global__ void gatednorm_bf_k(const bf16* __restrict__ o, const bf16* __restrict__ gate,
                               const float* __restrict__ onw, bf16* __restrict__ attn) {
  int wid = (blockIdx.x * blockDim.x + threadIdx.x) >> 6;
  int lane = threadIdx.x & 63;
  const bf16* orow = o + (size_t)wid * DVn;
  const bf16* grow = gate + (size_t)wid * DVn;
  bf16* arow = attn + (size_t)wid * DVn;
  float v0 = __bfloat162float(orow[lane]);
  float v1 = (lane < 32) ? __bfloat162float(orow[64 + lane]) : 0.f;
  float ss = v0 * v0 + v1 * v1;
  for (int m = 32; m >= 1; m >>= 1) ss += __shfl_xor(ss, m, 64);
  float rs = rsqrtf(ss * (1.f / DVn) + 1e-5f);
  float g0 = __bfloat162float(grow[lane]);
  arow[lane] = __float2bfloat16(v0 * rs * onw[lane] * siluf(g0));
  if (lane < 32) {
    float g1 = __bfloat162float(grow[64 + lane]);
    arow[64 + lane] = __float2bfloat16(v1 * rs * onw[64 + lane] * siluf(g1));
  }
}

extern "C" void kernel_launch(void* const* d_in, const int* in_sizes, int n_in,
                              void* d_out, int out_size, void* d_ws, size_t ws_size,
                              hipStream_t stream) {
  const float* x       = (const float*)d_in[0];
  const float* norm1_w = (const float*)d_in[1];
  const float* q_w     = (const float*)d_in[2];
  const float* k_w     = (const float*)d_in[3];
  const float* v_w     = (const float*)d_in[4];
  const float* cq_w    = (const float*)d_in[5];
  const float* ck_w    = (const float*)d_in[6];
  const float* cv_w    = (const float*)d_in[7];
  const float* b_w     = (const float*)d_in[8];
  const float* a_w     = (const float*)d_in[9];
  const float* A_log   = (const float*)d_in[10];
  const float* dt_bias = (const float*)d_in[11];
  const float* g_w     = (const float*)d_in[12];
  const float* o_norm_w= (const float*)d_in[13];
  const float* o_w     = (const float*)d_in[14];
  const float* norm2_w = (const float*)d_in[15];
  const float* gate_w  = (const float*)d_in[16];
  const float* up_w    = (const float*)d_in[17];
  const float* down_w  = (const float*)d_in[18];
  char* wsb = (char*)d_ws;
  float* out = (float*)d_out;

  bf16*  hbf   = (bf16*)(wsb + WO_HBF);
  bf16*  qkvr  = (bf16*)(wsb + WO_QKVR);
  bf16*  qkvc  = (bf16*)(wsb + WO_QKVC);
  bf16*  oscb  = (bf16*)(wsb + WO_OSC);
  bf16*  attn  = (bf16*)(wsb + WO_ATTN);
  bf16*  actb  = (bf16*)(wsb + WO_ACT);
  bf16*  gateb = (bf16*)(wsb + WO_GATE);
  float* x1    = (float*)(wsb + WO_X1);
  float* ba    = (float*)(wsb + WO_BA);
  float* Gc    = (float*)(wsb + WO_GC);
  bf16*  Tg    = (bf16*)(wsb + WO_T);
  bf16*  Uvg   = (bf16*)(wsb + WO_UV);
  bf16*  A_g   = (bf16*)(wsb + WO_A);
  bf16*  B_g   = (bf16*)(wsb + WO_B);
  bf16*  St_g  = (bf16*)(wsb + WO_ST);
  bf16*  wb    = (bf16*)(wsb + WO_WB);

  dim3 tb(32, 8);
  // 0. transpose-cast weights to bf16 [N][K]
  tcast_k<<<dim3(24, 32), tb, 0, stream>>>(q_w,    wb + WB_QKVT,              1024, 768);
  tcast_k<<<dim3(24, 32), tb, 0, stream>>>(k_w,    wb + WB_QKVT + 768 * 1024, 1024, 768);
  tcast_k<<<dim3(48, 32), tb, 0, stream>>>(v_w,    wb + WB_QKVT + 1536 * 1024,1024, 1536);
  tcast_k<<<dim3(48, 32), tb, 0, stream>>>(g_w,    wb + WB_GT,                1024, 1536);
  tcast_k<<<dim3(32, 48), tb, 0, stream>>>(o_w,    wb + WB_OT,                1536, 1024);
  tcast_k<<<dim3(96, 32), tb, 0, stream>>>(gate_w, wb + WB_GATET,             1024, 3072);
  tcast_k<<<dim3(96, 32), tb, 0, stream>>>(up_w,   wb + WB_UPT,               1024, 3072);
  tcast_k<<<dim3(32, 96), tb, 0, stream>>>(down_w, wb + WB_DOWNT,             3072, 1024);
  tcast_k<<<dim3(1, 32),  tb, 0, stream>>>(b_w,    wb + WB_ABT,               1024, 16);
  tcast_k<<<dim3(1, 32),  tb, 0, stream>>>(a_w,    wb + WB_ABT + 16 * 1024,   1024, 16);

  // 1. h_bf = rmsnorm(x)
  rmsnorm_bf_k<<<BT, 256, 0, stream>>>(x, norm1_w, hbf);
  // 2. projections
  gemm_mfma<<<dim3(24, 64), 256, 0, stream>>>(hbf, wb + WB_QKVT, qkvr, nullptr, 3072, 1024, 3072, 3);
  gemm_mfma<<<dim3(1, 64), 256, 0, stream>>>(hbf, wb + WB_ABT, ba, nullptr, 32, 1024, 32, 0);
  gemm_mfma<<<dim3(12, 64), 256, 0, stream>>>(hbf, wb + WB_GT, gateb, nullptr, 1536, 1024, 1536, 3);
  // 3. conv+silu, l2norm, beta/g
  convsilu2_k<<<dim3(QKVC / 256, BT / 8), 256, 0, stream>>>(qkvr, qkvc, cq_w, ck_w, cv_w);
  l2norm_k<<<(BT * 32) / 4, 256, 0, stream>>>(qkvc);
  betag_k<<<(BT * Hn) / 256, 256, 0, stream>>>(ba, A_log, dt_bias);
  // 4. chunked gated delta rule
  dn_p1<<<Bn * Hn * NC, 256, 0, stream>>>(qkvc, ba, Gc, Tg, Uvg);
  dn_p2a<<<Bn * Hn * NC, 256, 0, stream>>>(qkvc, ba, Gc, Tg, Uvg, A_g, B_g);
  dn_p2b<<<Bn * Hn, 256, 0, stream>>>(A_g, B_g, St_g);
  dn_p2c<<<Bn * Hn * NC, 256, 0, stream>>>(qkvc, ba, Gc, Tg, Uvg, St_g, oscb);
  // 5. gated RMSNorm -> attn
  gatednorm_bf_k<<<(BT * Hn) / 4, 256, 0, stream>>>(oscb, gateb, o_norm_w, attn);
  // 6. x1 = x + attn @ o_w
  gemm_mfma<<<dim3(8, 64), 256, 0, stream>>>(attn, wb + WB_OT, x1, x, 1024, 1536, 1024, 0);
  // 7. h2 = rmsnorm(x1)
  rmsnorm_bf_k<<<BT, 256, 0, stream>>>(x1, norm2_w, hbf);
  // 8. act = silu(h2@gate_w) * (h2@up_w)
  gemm_mfma<<<dim3(24, 64), 256, 0, stream>>>(hbf, wb + WB_GATET, actb, nullptr, 3072, 1024, 3072, 1);
  gemm_mfma<<<dim3(24, 64), 256, 0, stream>>>(hbf, wb + WB_UPT, actb, nullptr, 3072, 1024, 3072, 2);
  // 9. out = x1 + act @ down_w
  gemm_mfma<<<dim3(8, 64), 256, 0, stream>>>(actb, wb + WB_DOWNT, out, x1, 1024, 3072, 1024, 0);
}